// Round 1
// baseline (769.850 us; speedup 1.0000x reference)
//
#include <hip/hip_runtime.h>

#define FD 128
#define NH 4
#define HF 512

__device__ __forceinline__ float lrelu(float x, float s) { return x > 0.f ? x : s * x; }

// ---------------- K1: xp = x @ W_gat   x:[n,128]  W:[128,512]  xp:[n,512]
__global__ __launch_bounds__(256) void k_xp(const float* __restrict__ x,
                                            const float* __restrict__ Wg,
                                            float* __restrict__ xp, int n) {
    __shared__ float xs[64][132];   // pad 132: conflict-free scalar row reads
    const int tid = threadIdx.x;
    const int r0 = blockIdx.x * 64;
#pragma unroll
    for (int i = 0; i < 8; ++i) {
        int flat = (tid + i * 256) * 4;
        int r = flat >> 7, k = flat & 127;
        int rr = min(r0 + r, n - 1);
        *reinterpret_cast<float4*>(&xs[r][k]) =
            *reinterpret_cast<const float4*>(&x[(size_t)rr * FD + k]);
    }
    __syncthreads();
    const int tr = tid >> 4, tc = tid & 15;
#pragma unroll 1
    for (int cc = 0; cc < 8; ++cc) {
        float acc[4][4] = {};
        const float* wp = &Wg[cc * 64 + 4 * tc];
#pragma unroll 4
        for (int k = 0; k < 128; ++k) {
            float4 wv = *reinterpret_cast<const float4*>(&wp[(size_t)k * HF]);
#pragma unroll
            for (int i = 0; i < 4; ++i) {
                float hv = xs[4 * tr + i][k];
                acc[i][0] += hv * wv.x; acc[i][1] += hv * wv.y;
                acc[i][2] += hv * wv.z; acc[i][3] += hv * wv.w;
            }
        }
#pragma unroll
        for (int i = 0; i < 4; ++i) {
            int row = r0 + 4 * tr + i;
            if (row < n) {
                float4 v = make_float4(acc[i][0], acc[i][1], acc[i][2], acc[i][3]);
                *reinterpret_cast<float4*>(&xp[(size_t)row * HF + cc * 64 + 4 * tc]) = v;
            }
        }
    }
}

// ---------------- K1b: a_src[n,h] = <xp[n,h,:], att_src[h,:]>, same for dst
__global__ __launch_bounds__(256) void k_att(const float* __restrict__ xp,
                                             const float* __restrict__ att_s,
                                             const float* __restrict__ att_d,
                                             float* __restrict__ a_s,
                                             float* __restrict__ a_d, int n) {
    const int w = threadIdx.x >> 6, l = threadIdx.x & 63;
    const int node = blockIdx.x * 4 + w;
    if (node >= n) return;
    const float4* xr = reinterpret_cast<const float4*>(&xp[(size_t)node * HF]);
    const float4* as4 = reinterpret_cast<const float4*>(att_s);
    const float4* ad4 = reinterpret_cast<const float4*>(att_d);
    float ps = 0.f, pd = 0.f;
#pragma unroll
    for (int j = 0; j < 2; ++j) {
        float4 v = xr[l * 2 + j], a = as4[l * 2 + j], b = ad4[l * 2 + j];
        ps += v.x * a.x + v.y * a.y + v.z * a.z + v.w * a.w;
        pd += v.x * b.x + v.y * b.y + v.z * b.z + v.w * b.w;
    }
#pragma unroll
    for (int m = 1; m <= 8; m <<= 1) { ps += __shfl_xor(ps, m); pd += __shfl_xor(pd, m); }
    if ((l & 15) == 0) {
        a_s[node * NH + (l >> 4)] = ps;
        a_d[node * NH + (l >> 4)] = pd;
    }
}

// ---------------- K2: degree count by dst
__global__ __launch_bounds__(256) void k_count(const int* __restrict__ dst,
                                               int* __restrict__ cnt, int e) {
    int i = blockIdx.x * 256 + threadIdx.x;
    if (i < e) atomicAdd(&cnt[dst[i]], 1);
}

// ---------------- K3: exclusive scan -> off[0..n], cur[i]=off[i]
__global__ __launch_bounds__(1024) void k_scan(const int* __restrict__ cnt,
                                               int* __restrict__ off,
                                               int* __restrict__ cur, int n) {
    __shared__ int stot[16];
    const int t = threadIdx.x;
    const int lane = t & 63, wid = t >> 6;
    if (t == 0) off[0] = 0;
    int carry = 0;
    for (int base = 0; base < n; base += 1024) {
        int idx = base + t;
        int v = (idx < n) ? cnt[idx] : 0;
        int incl = v;
#pragma unroll
        for (int d = 1; d < 64; d <<= 1) {
            int o = __shfl_up(incl, d);
            if (lane >= d) incl += o;
        }
        if (lane == 63) stot[wid] = incl;
        __syncthreads();
        int woff = 0, total = 0;
#pragma unroll
        for (int i = 0; i < 16; ++i) {
            int s = stot[i];
            if (i < wid) woff += s;
            total += s;
        }
        incl += woff;
        if (idx < n) { off[idx + 1] = carry + incl; cur[idx] = carry + incl - v; }
        carry += total;
        __syncthreads();
    }
}

// ---------------- K4: scatter edges into CSR slots, with leaky(0.2) logits
__global__ __launch_bounds__(256) void k_scatter(const int* __restrict__ es,
                                                 const int* __restrict__ ed,
                                                 const float* __restrict__ a_s,
                                                 const float* __restrict__ a_d,
                                                 int* __restrict__ cur,
                                                 int* __restrict__ ssort,
                                                 float4* __restrict__ asort, int e) {
    int i = blockIdx.x * 256 + threadIdx.x;
    if (i >= e) return;
    int s = es[i], d = ed[i];
    const float4 as = *reinterpret_cast<const float4*>(&a_s[(size_t)s * NH]);
    const float4 ad = *reinterpret_cast<const float4*>(&a_d[(size_t)d * NH]);
    float4 al;
    al.x = lrelu(as.x + ad.x, 0.2f);
    al.y = lrelu(as.y + ad.y, 0.2f);
    al.z = lrelu(as.z + ad.z, 0.2f);
    al.w = lrelu(as.w + ad.w, 0.2f);
    int pos = atomicAdd(&cur[d], 1);
    ssort[pos] = s;
    asort[pos] = al;
}

// ---------------- K5: per-node softmax + weighted aggregation -> h1 (leaky 0.01, +bias)
__global__ __launch_bounds__(256) void k_aggr(const float* __restrict__ xp,
                                              const float* __restrict__ a_s,
                                              const float* __restrict__ a_d,
                                              const int* __restrict__ off,
                                              const int* __restrict__ ssort,
                                              const float* __restrict__ asort,
                                              const float* __restrict__ bias,
                                              float* __restrict__ h1, int n) {
    const int nid = blockIdx.x;
    const int w = threadIdx.x >> 6, l = threadIdx.x & 63;   // wave w owns head w
    const int o0 = off[nid], deg = off[nid + 1] - o0;
    const float aS = lrelu(a_s[nid * NH + w] + a_d[nid * NH + w], 0.2f);
    // max over incoming edges + self
    float m = aS;
    for (int e = l; e < deg; e += 64) m = fmaxf(m, asort[(size_t)(o0 + e) * 4 + w]);
#pragma unroll
    for (int d = 1; d < 64; d <<= 1) m = fmaxf(m, __shfl_xor(m, d));
    // denom
    float ss = 0.f;
    for (int e = l; e < deg; e += 64) ss += __expf(asort[(size_t)(o0 + e) * 4 + w] - m);
#pragma unroll
    for (int d = 1; d < 64; d <<= 1) ss += __shfl_xor(ss, d);
    ss += __expf(aS - m);
    const float inv = 1.f / ss;
    const int c = w * FD + 2 * l;   // this thread's 2 feature elements
    float2 acc;
    {
        float wS = __expf(aS - m) * inv;
        float2 v = *reinterpret_cast<const float2*>(&xp[(size_t)nid * HF + c]);
        acc.x = v.x * wS; acc.y = v.y * wS;
    }
    for (int e = 0; e < deg; ++e) {
        int s = ssort[o0 + e];
        float wgt = __expf(asort[(size_t)(o0 + e) * 4 + w] - m) * inv;
        float2 u = *reinterpret_cast<const float2*>(&xp[(size_t)s * HF + c]);
        acc.x += u.x * wgt; acc.y += u.y * wgt;
    }
    acc.x = lrelu(acc.x + bias[c], 0.01f);
    acc.y = lrelu(acc.y + bias[c + 1], 0.01f);
    *reinterpret_cast<float2*>(&h1[(size_t)nid * HF + c]) = acc;
}

// ---------------- K6: hm = h1 @ W_mha + b_mha + x   [n,512]@[512,128]
__global__ __launch_bounds__(256) void k_mha(const float* __restrict__ h1,
                                             const float* __restrict__ Wm,
                                             const float* __restrict__ bm,
                                             const float* __restrict__ x,
                                             float* __restrict__ hm, int n) {
    __shared__ float hs[64][68];
    __shared__ float ws[64][132];
    const int tid = threadIdx.x;
    const int r0 = blockIdx.x * 64;
    const int tr = tid >> 4, tc = tid & 15;
    float acc[4][8] = {};
#pragma unroll 1
    for (int kc = 0; kc < 8; ++kc) {
#pragma unroll
        for (int i = 0; i < 4; ++i) {
            int flat = (tid + i * 256) * 4;
            int r = flat >> 6, k = flat & 63;
            int rr = min(r0 + r, n - 1);
            *reinterpret_cast<float4*>(&hs[r][k]) =
                *reinterpret_cast<const float4*>(&h1[(size_t)rr * HF + kc * 64 + k]);
        }
#pragma unroll
        for (int i = 0; i < 8; ++i) {
            int flat = (tid + i * 256) * 4;
            int k = flat >> 7, c = flat & 127;
            *reinterpret_cast<float4*>(&ws[k][c]) =
                *reinterpret_cast<const float4*>(&Wm[(size_t)(kc * 64 + k) * FD + c]);
        }
        __syncthreads();
#pragma unroll 2
        for (int k = 0; k < 64; ++k) {
            float4 w0 = *reinterpret_cast<const float4*>(&ws[k][4 * tc]);
            float4 w1 = *reinterpret_cast<const float4*>(&ws[k][64 + 4 * tc]);
#pragma unroll
            for (int i = 0; i < 4; ++i) {
                float hv = hs[4 * tr + i][k];
                acc[i][0] += hv * w0.x; acc[i][1] += hv * w0.y;
                acc[i][2] += hv * w0.z; acc[i][3] += hv * w0.w;
                acc[i][4] += hv * w1.x; acc[i][5] += hv * w1.y;
                acc[i][6] += hv * w1.z; acc[i][7] += hv * w1.w;
            }
        }
        __syncthreads();
    }
    float4 b0 = *reinterpret_cast<const float4*>(&bm[4 * tc]);
    float4 b1v = *reinterpret_cast<const float4*>(&bm[64 + 4 * tc]);
#pragma unroll
    for (int i = 0; i < 4; ++i) {
        int row = r0 + 4 * tr + i;
        if (row < n) {
            float4 x0 = *reinterpret_cast<const float4*>(&x[(size_t)row * FD + 4 * tc]);
            float4 x1 = *reinterpret_cast<const float4*>(&x[(size_t)row * FD + 64 + 4 * tc]);
            float4 o0 = make_float4(acc[i][0] + b0.x + x0.x, acc[i][1] + b0.y + x0.y,
                                    acc[i][2] + b0.z + x0.z, acc[i][3] + b0.w + x0.w);
            float4 o1 = make_float4(acc[i][4] + b1v.x + x1.x, acc[i][5] + b1v.y + x1.y,
                                    acc[i][6] + b1v.z + x1.z, acc[i][7] + b1v.w + x1.w);
            *reinterpret_cast<float4*>(&hm[(size_t)row * FD + 4 * tc]) = o0;
            *reinterpret_cast<float4*>(&hm[(size_t)row * FD + 64 + 4 * tc]) = o1;
        }
    }
}

// ---------------- K7: out = lrelu(hm@W1+b1,0.01)@W2 + b2 + hm
__global__ __launch_bounds__(256) void k_ffn(const float* __restrict__ hm,
                                             const float* __restrict__ W1,
                                             const float* __restrict__ b1,
                                             const float* __restrict__ W2,
                                             const float* __restrict__ b2,
                                             float* __restrict__ out, int n) {
    __shared__ float hs[32][132];
    __shared__ float ts[32][132];
    const int tid = threadIdx.x;
    const int r0 = blockIdx.x * 32;
    const int tr = tid >> 4, tc = tid & 15;
#pragma unroll
    for (int i = 0; i < 4; ++i) {
        int flat = (tid + i * 256) * 4;
        int r = flat >> 7, k = flat & 127;
        int rr = min(r0 + r, n - 1);
        *reinterpret_cast<float4*>(&hs[r][k]) =
            *reinterpret_cast<const float4*>(&hm[(size_t)rr * FD + k]);
    }
    __syncthreads();
    {
        float acc[2][8] = {};
#pragma unroll 4
        for (int k = 0; k < 128; ++k) {
            float4 w0 = *reinterpret_cast<const float4*>(&W1[(size_t)k * FD + 4 * tc]);
            float4 w1 = *reinterpret_cast<const float4*>(&W1[(size_t)k * FD + 64 + 4 * tc]);
#pragma unroll
            for (int i = 0; i < 2; ++i) {
                float hv = hs[2 * tr + i][k];
                acc[i][0] += hv * w0.x; acc[i][1] += hv * w0.y;
                acc[i][2] += hv * w0.z; acc[i][3] += hv * w0.w;
                acc[i][4] += hv * w1.x; acc[i][5] += hv * w1.y;
                acc[i][6] += hv * w1.z; acc[i][7] += hv * w1.w;
            }
        }
        float4 bb0 = *reinterpret_cast<const float4*>(&b1[4 * tc]);
        float4 bb1 = *reinterpret_cast<const float4*>(&b1[64 + 4 * tc]);
#pragma unroll
        for (int i = 0; i < 2; ++i) {
            float4 t0 = make_float4(lrelu(acc[i][0] + bb0.x, 0.01f), lrelu(acc[i][1] + bb0.y, 0.01f),
                                    lrelu(acc[i][2] + bb0.z, 0.01f), lrelu(acc[i][3] + bb0.w, 0.01f));
            float4 t1 = make_float4(lrelu(acc[i][4] + bb1.x, 0.01f), lrelu(acc[i][5] + bb1.y, 0.01f),
                                    lrelu(acc[i][6] + bb1.z, 0.01f), lrelu(acc[i][7] + bb1.w, 0.01f));
            *reinterpret_cast<float4*>(&ts[2 * tr + i][4 * tc]) = t0;
            *reinterpret_cast<float4*>(&ts[2 * tr + i][64 + 4 * tc]) = t1;
        }
    }
    __syncthreads();
    {
        float acc[2][8] = {};
#pragma unroll 4
        for (int k = 0; k < 128; ++k) {
            float4 w0 = *reinterpret_cast<const float4*>(&W2[(size_t)k * FD + 4 * tc]);
            float4 w1 = *reinterpret_cast<const float4*>(&W2[(size_t)k * FD + 64 + 4 * tc]);
#pragma unroll
            for (int i = 0; i < 2; ++i) {
                float hv = ts[2 * tr + i][k];
                acc[i][0] += hv * w0.x; acc[i][1] += hv * w0.y;
                acc[i][2] += hv * w0.z; acc[i][3] += hv * w0.w;
                acc[i][4] += hv * w1.x; acc[i][5] += hv * w1.y;
                acc[i][6] += hv * w1.z; acc[i][7] += hv * w1.w;
            }
        }
        float4 bb0 = *reinterpret_cast<const float4*>(&b2[4 * tc]);
        float4 bb1 = *reinterpret_cast<const float4*>(&b2[64 + 4 * tc]);
#pragma unroll
        for (int i = 0; i < 2; ++i) {
            int row = r0 + 2 * tr + i;
            if (row < n) {
                float4 r0v = *reinterpret_cast<const float4*>(&hs[2 * tr + i][4 * tc]);
                float4 r1v = *reinterpret_cast<const float4*>(&hs[2 * tr + i][64 + 4 * tc]);
                float4 o0 = make_float4(acc[i][0] + bb0.x + r0v.x, acc[i][1] + bb0.y + r0v.y,
                                        acc[i][2] + bb0.z + r0v.z, acc[i][3] + bb0.w + r0v.w);
                float4 o1 = make_float4(acc[i][4] + bb1.x + r1v.x, acc[i][5] + bb1.y + r1v.y,
                                        acc[i][6] + bb1.z + r1v.z, acc[i][7] + bb1.w + r1v.w);
                *reinterpret_cast<float4*>(&out[(size_t)row * FD + 4 * tc]) = o0;
                *reinterpret_cast<float4*>(&out[(size_t)row * FD + 64 + 4 * tc]) = o1;
            }
        }
    }
}

extern "C" void kernel_launch(void* const* d_in, const int* in_sizes, int n_in,
                              void* d_out, int out_size, void* d_ws, size_t ws_size,
                              hipStream_t stream) {
    const float* x     = (const float*)d_in[0];
    const int*   ei    = (const int*)d_in[1];
    const float* Wg    = (const float*)d_in[2];
    const float* att_s = (const float*)d_in[3];
    const float* att_d = (const float*)d_in[4];
    const float* biasg = (const float*)d_in[5];
    const float* Wm    = (const float*)d_in[6];
    const float* bm    = (const float*)d_in[7];
    const float* W1    = (const float*)d_in[8];
    const float* b1    = (const float*)d_in[9];
    const float* W2    = (const float*)d_in[10];
    const float* b2    = (const float*)d_in[11];
    float* out = (float*)d_out;

    const int n = in_sizes[0] / FD;
    const int E = in_sizes[1] / 2;
    const int* esrc = ei;
    const int* edst = ei + E;

    char* w = (char*)d_ws;
    size_t o = 0;
    auto alloc = [&](size_t b) { void* p = w + o; o = (o + b + 255) & ~(size_t)255; return p; };
    float* xp    = (float*)alloc((size_t)n * HF * 4);
    float* h1    = (float*)alloc((size_t)n * HF * 4);
    float* hm    = (float*)alloc((size_t)n * FD * 4);
    float* a_s   = (float*)alloc((size_t)n * NH * 4);
    float* a_d   = (float*)alloc((size_t)n * NH * 4);
    int*   cnt   = (int*)alloc((size_t)n * 4);
    int*   offs  = (int*)alloc((size_t)(n + 1) * 4);
    int*   cur   = (int*)alloc((size_t)n * 4);
    int*   ssort = (int*)alloc((size_t)E * 4);
    float* asort = (float*)alloc((size_t)E * 16);

    hipMemsetAsync(cnt, 0, (size_t)n * 4, stream);
    k_xp<<<(n + 63) / 64, 256, 0, stream>>>(x, Wg, xp, n);
    k_att<<<(n + 3) / 4, 256, 0, stream>>>(xp, att_s, att_d, a_s, a_d, n);
    k_count<<<(E + 255) / 256, 256, 0, stream>>>(edst, cnt, E);
    k_scan<<<1, 1024, 0, stream>>>(cnt, offs, cur, n);
    k_scatter<<<(E + 255) / 256, 256, 0, stream>>>(esrc, edst, a_s, a_d, cur, ssort,
                                                   (float4*)asort, E);
    k_aggr<<<n, 256, 0, stream>>>(xp, a_s, a_d, offs, ssort, asort, biasg, h1, n);
    k_mha<<<(n + 63) / 64, 256, 0, stream>>>(h1, Wm, bm, x, hm, n);
    k_ffn<<<(n + 31) / 32, 256, 0, stream>>>(hm, W1, b1, W2, b2, out, n);
}

// Round 2
// 495.057 us; speedup vs baseline: 1.5551x; 1.5551x over previous
//
#include <hip/hip_runtime.h>

#define FD 128
#define NH 4
#define HF 512

typedef __attribute__((ext_vector_type(8))) short short8;
typedef __attribute__((ext_vector_type(4))) float v4f;

__device__ __forceinline__ float lrelu(float x, float s) { return x > 0.f ? x : s * x; }

__device__ __forceinline__ unsigned short f2bf(float f) {
    unsigned int u = __float_as_uint(f);
    u += 0x7FFFu + ((u >> 16) & 1u);          // RNE
    return (unsigned short)(u >> 16);
}
__device__ __forceinline__ float bf2f(unsigned short u) {
    return __uint_as_float((unsigned int)u << 16);
}

// ---------------- cast x -> bf16
__global__ __launch_bounds__(256) void k_cx(const float* __restrict__ x,
                                            unsigned short* __restrict__ xb, int tot4) {
    int i = blockIdx.x * 256 + threadIdx.x;
    if (i < tot4) {
        float4 v = reinterpret_cast<const float4*>(x)[i];
        unsigned short o[4] = {f2bf(v.x), f2bf(v.y), f2bf(v.z), f2bf(v.w)};
        *reinterpret_cast<uint2*>(&xb[i * 4]) =
            make_uint2((unsigned)o[0] | ((unsigned)o[1] << 16),
                       (unsigned)o[2] | ((unsigned)o[3] << 16));
    }
}

// ---------------- transpose-cast weight W[K][N] -> WT[N][K] bf16
__global__ __launch_bounds__(256) void k_tw(const float* __restrict__ W,
                                            unsigned short* __restrict__ WT, int K, int N) {
    int i = blockIdx.x * 256 + threadIdx.x;
    if (i < N * K) {
        int nn = i / K, k = i - nn * K;
        WT[i] = f2bf(W[(size_t)k * N + nn]);
    }
}

// ---------------- generic MFMA GEMM: C[n x Ntot] = A[n x K](bf16) @ BT[Ntot x K](bf16)
// MODE 0: store bf16            (xp)
// MODE 1: +bias +resid(fp32,stride Ntot) -> store fp32 AND bf16   (mha)
// MODE 2: lrelu(+bias,0.01) -> store bf16                          (ffn1)
// MODE 3: +bias +resid -> store fp32                               (ffn2)
template <int K, int MODE>
__global__ __launch_bounds__(256) void k_gemm(const unsigned short* __restrict__ A,
                                              const unsigned short* __restrict__ BT,
                                              const float* __restrict__ bias,
                                              const float* __restrict__ resid,
                                              unsigned short* __restrict__ outb,
                                              float* __restrict__ outf,
                                              int n, int Ntot) {
    const int nb = Ntot >> 6;
    const int n0 = (blockIdx.x % nb) * 64;
    const int m0 = (blockIdx.x / nb) * 64;
    const int wv = threadIdx.x >> 6, l = threadIdx.x & 63;
    const int mw = m0 + wv * 16;
    const int rA = l & 15;                 // A row within tile / B col within tile
    const int kg = (l >> 4) * 8;           // k sub-offset
    const int amr = min(mw + rA, n - 1);

    v4f acc[4];
#pragma unroll
    for (int t = 0; t < 4; ++t) acc[t] = (v4f){0.f, 0.f, 0.f, 0.f};

#pragma unroll 4
    for (int kk = 0; kk < K / 32; ++kk) {
        short8 a = *reinterpret_cast<const short8*>(&A[(size_t)amr * K + kk * 32 + kg]);
#pragma unroll
        for (int nt = 0; nt < 4; ++nt) {
            short8 b = *reinterpret_cast<const short8*>(
                &BT[(size_t)(n0 + nt * 16 + rA) * K + kk * 32 + kg]);
            acc[nt] = __builtin_amdgcn_mfma_f32_16x16x32_bf16(a, b, acc[nt], 0, 0, 0);
        }
    }

#pragma unroll
    for (int nt = 0; nt < 4; ++nt) {
        const int col = n0 + nt * 16 + (l & 15);
#pragma unroll
        for (int i = 0; i < 4; ++i) {
            const int r = mw + (l >> 4) * 4 + i;
            if (r < n) {
                float v = acc[nt][i];
                if (MODE == 0) {
                    outb[(size_t)r * Ntot + col] = f2bf(v);
                } else if (MODE == 1) {
                    v += bias[col] + resid[(size_t)r * Ntot + col];
                    outf[(size_t)r * Ntot + col] = v;
                    outb[(size_t)r * Ntot + col] = f2bf(v);
                } else if (MODE == 2) {
                    v = lrelu(v + bias[col], 0.01f);
                    outb[(size_t)r * Ntot + col] = f2bf(v);
                } else {
                    v += bias[col] + resid[(size_t)r * Ntot + col];
                    outf[(size_t)r * Ntot + col] = v;
                }
            }
        }
    }
}

// ---------------- a_src/a_dst from bf16 xp
__global__ __launch_bounds__(256) void k_att(const unsigned short* __restrict__ xpb,
                                             const float* __restrict__ att_s,
                                             const float* __restrict__ att_d,
                                             float* __restrict__ a_s,
                                             float* __restrict__ a_d, int n) {
    const int w = threadIdx.x >> 6, l = threadIdx.x & 63;
    const int node = blockIdx.x * 4 + w;
    if (node >= n) return;
    const short8 v = *reinterpret_cast<const short8*>(&xpb[(size_t)node * HF + l * 8]);
    const int head = l >> 4;
    const int f0 = (l & 15) * 8;
    float ps = 0.f, pd = 0.f;
#pragma unroll
    for (int j = 0; j < 8; ++j) {
        float xv = bf2f((unsigned short)v[j]);
        ps += xv * att_s[head * FD + f0 + j];
        pd += xv * att_d[head * FD + f0 + j];
    }
#pragma unroll
    for (int m = 1; m <= 8; m <<= 1) { ps += __shfl_xor(ps, m); pd += __shfl_xor(pd, m); }
    if ((l & 15) == 0) {
        a_s[node * NH + head] = ps;
        a_d[node * NH + head] = pd;
    }
}

// ---------------- degree count by dst
__global__ __launch_bounds__(256) void k_count(const int* __restrict__ dst,
                                               int* __restrict__ cnt, int e) {
    int i = blockIdx.x * 256 + threadIdx.x;
    if (i < e) atomicAdd(&cnt[dst[i]], 1);
}

// ---------------- exclusive scan -> off[0..n], cur[i]=off[i]
__global__ __launch_bounds__(1024) void k_scan(const int* __restrict__ cnt,
                                               int* __restrict__ off,
                                               int* __restrict__ cur, int n) {
    __shared__ int stot[16];
    const int t = threadIdx.x;
    const int lane = t & 63, wid = t >> 6;
    if (t == 0) off[0] = 0;
    int carry = 0;
    for (int base = 0; base < n; base += 1024) {
        int idx = base + t;
        int v = (idx < n) ? cnt[idx] : 0;
        int incl = v;
#pragma unroll
        for (int d = 1; d < 64; d <<= 1) {
            int o = __shfl_up(incl, d);
            if (lane >= d) incl += o;
        }
        if (lane == 63) stot[wid] = incl;
        __syncthreads();
        int woff = 0, total = 0;
#pragma unroll
        for (int i = 0; i < 16; ++i) {
            int s = stot[i];
            if (i < wid) woff += s;
            total += s;
        }
        incl += woff;
        if (idx < n) { off[idx + 1] = carry + incl; cur[idx] = carry + incl - v; }
        carry += total;
        __syncthreads();
    }
}

// ---------------- scatter edges into CSR slots, with leaky(0.2) logits
__global__ __launch_bounds__(256) void k_scatter(const int* __restrict__ es,
                                                 const int* __restrict__ ed,
                                                 const float* __restrict__ a_s,
                                                 const float* __restrict__ a_d,
                                                 int* __restrict__ cur,
                                                 int* __restrict__ ssort,
                                                 float4* __restrict__ asort, int e) {
    int i = blockIdx.x * 256 + threadIdx.x;
    if (i >= e) return;
    int s = es[i], d = ed[i];
    const float4 as = *reinterpret_cast<const float4*>(&a_s[(size_t)s * NH]);
    const float4 ad = *reinterpret_cast<const float4*>(&a_d[(size_t)d * NH]);
    float4 al;
    al.x = lrelu(as.x + ad.x, 0.2f);
    al.y = lrelu(as.y + ad.y, 0.2f);
    al.z = lrelu(as.z + ad.z, 0.2f);
    al.w = lrelu(as.w + ad.w, 0.2f);
    int pos = atomicAdd(&cur[d], 1);
    ssort[pos] = s;
    asort[pos] = al;
}

// ---------------- per-node softmax + weighted aggregation -> h1 bf16 (+bias, leaky 0.01)
__global__ __launch_bounds__(256) void k_aggr(const unsigned short* __restrict__ xpb,
                                              const float* __restrict__ a_s,
                                              const float* __restrict__ a_d,
                                              const int* __restrict__ off,
                                              const int* __restrict__ ssort,
                                              const float* __restrict__ asort,
                                              const float* __restrict__ bias,
                                              unsigned short* __restrict__ h1b, int n) {
    const int nid = blockIdx.x;
    const int w = threadIdx.x >> 6, l = threadIdx.x & 63;   // wave w owns head w
    const int o0 = off[nid], deg = off[nid + 1] - o0;
    const float aS = lrelu(a_s[nid * NH + w] + a_d[nid * NH + w], 0.2f);
    float m = aS;
    for (int e = l; e < deg; e += 64) m = fmaxf(m, asort[(size_t)(o0 + e) * 4 + w]);
#pragma unroll
    for (int d = 1; d < 64; d <<= 1) m = fmaxf(m, __shfl_xor(m, d));
    float ss = 0.f;
    for (int e = l; e < deg; e += 64) ss += __expf(asort[(size_t)(o0 + e) * 4 + w] - m);
#pragma unroll
    for (int d = 1; d < 64; d <<= 1) ss += __shfl_xor(ss, d);
    ss += __expf(aS - m);
    const float inv = 1.f / ss;
    const int c = w * FD + 2 * l;   // this thread's 2 feature elements
    float ax, ay;
    {
        float wS = __expf(aS - m) * inv;
        unsigned int u = *reinterpret_cast<const unsigned int*>(&xpb[(size_t)nid * HF + c]);
        ax = bf2f((unsigned short)u) * wS;
        ay = bf2f((unsigned short)(u >> 16)) * wS;
    }
    int e = 0;
    for (; e + 1 < deg; e += 2) {
        int s0 = ssort[o0 + e], s1 = ssort[o0 + e + 1];
        float w0 = __expf(asort[(size_t)(o0 + e) * 4 + w] - m) * inv;
        float w1 = __expf(asort[(size_t)(o0 + e + 1) * 4 + w] - m) * inv;
        unsigned int u0 = *reinterpret_cast<const unsigned int*>(&xpb[(size_t)s0 * HF + c]);
        unsigned int u1 = *reinterpret_cast<const unsigned int*>(&xpb[(size_t)s1 * HF + c]);
        ax += bf2f((unsigned short)u0) * w0 + bf2f((unsigned short)u1) * w1;
        ay += bf2f((unsigned short)(u0 >> 16)) * w0 + bf2f((unsigned short)(u1 >> 16)) * w1;
    }
    if (e < deg) {
        int s0 = ssort[o0 + e];
        float w0 = __expf(asort[(size_t)(o0 + e) * 4 + w] - m) * inv;
        unsigned int u0 = *reinterpret_cast<const unsigned int*>(&xpb[(size_t)s0 * HF + c]);
        ax += bf2f((unsigned short)u0) * w0;
        ay += bf2f((unsigned short)(u0 >> 16)) * w0;
    }
    ax = lrelu(ax + bias[c], 0.01f);
    ay = lrelu(ay + bias[c + 1], 0.01f);
    *reinterpret_cast<unsigned int*>(&h1b[(size_t)nid * HF + c]) =
        (unsigned)f2bf(ax) | ((unsigned)f2bf(ay) << 16);
}

extern "C" void kernel_launch(void* const* d_in, const int* in_sizes, int n_in,
                              void* d_out, int out_size, void* d_ws, size_t ws_size,
                              hipStream_t stream) {
    const float* x     = (const float*)d_in[0];
    const int*   ei    = (const int*)d_in[1];
    const float* Wg    = (const float*)d_in[2];
    const float* att_s = (const float*)d_in[3];
    const float* att_d = (const float*)d_in[4];
    const float* biasg = (const float*)d_in[5];
    const float* Wm    = (const float*)d_in[6];
    const float* bm    = (const float*)d_in[7];
    const float* W1    = (const float*)d_in[8];
    const float* b1    = (const float*)d_in[9];
    const float* W2    = (const float*)d_in[10];
    const float* b2    = (const float*)d_in[11];
    float* out = (float*)d_out;

    const int n = in_sizes[0] / FD;
    const int E = in_sizes[1] / 2;
    const int* esrc = ei;
    const int* edst = ei + E;

    char* w = (char*)d_ws;
    size_t o = 0;
    auto alloc = [&](size_t b) { void* p = w + o; o = (o + b + 255) & ~(size_t)255; return p; };
    unsigned short* x_b  = (unsigned short*)alloc((size_t)n * FD * 2);
    unsigned short* WgT  = (unsigned short*)alloc((size_t)FD * HF * 2);
    unsigned short* WmT  = (unsigned short*)alloc((size_t)HF * FD * 2);
    unsigned short* W1T  = (unsigned short*)alloc((size_t)FD * FD * 2);
    unsigned short* W2T  = (unsigned short*)alloc((size_t)FD * FD * 2);
    unsigned short* xp_b = (unsigned short*)alloc((size_t)n * HF * 2);
    unsigned short* h1_b = (unsigned short*)alloc((size_t)n * HF * 2);
    float*          hm_f = (float*)alloc((size_t)n * FD * 4);
    unsigned short* hm_b = (unsigned short*)alloc((size_t)n * FD * 2);
    unsigned short* t_b  = (unsigned short*)alloc((size_t)n * FD * 2);
    float* a_s   = (float*)alloc((size_t)n * NH * 4);
    float* a_d   = (float*)alloc((size_t)n * NH * 4);
    int*   cnt   = (int*)alloc((size_t)n * 4);
    int*   offs  = (int*)alloc((size_t)(n + 1) * 4);
    int*   cur   = (int*)alloc((size_t)n * 4);
    int*   ssort = (int*)alloc((size_t)E * 4);
    float* asort = (float*)alloc((size_t)E * 16);

    hipMemsetAsync(cnt, 0, (size_t)n * 4, stream);
    k_count<<<(E + 255) / 256, 256, 0, stream>>>(edst, cnt, E);
    k_cx<<<((n * FD / 4) + 255) / 256, 256, 0, stream>>>(x, x_b, n * FD / 4);
    k_tw<<<(FD * HF + 255) / 256, 256, 0, stream>>>(Wg, WgT, FD, HF);
    k_tw<<<(HF * FD + 255) / 256, 256, 0, stream>>>(Wm, WmT, HF, FD);
    k_tw<<<(FD * FD + 255) / 256, 256, 0, stream>>>(W1, W1T, FD, FD);
    k_tw<<<(FD * FD + 255) / 256, 256, 0, stream>>>(W2, W2T, FD, FD);

    const int mb = (n + 63) / 64;
    // xp = x @ Wg  -> bf16
    k_gemm<FD, 0><<<mb * (HF / 64), 256, 0, stream>>>(x_b, WgT, nullptr, nullptr,
                                                      xp_b, nullptr, n, HF);
    k_att<<<(n + 3) / 4, 256, 0, stream>>>(xp_b, att_s, att_d, a_s, a_d, n);
    k_scan<<<1, 1024, 0, stream>>>(cnt, offs, cur, n);
    k_scatter<<<(E + 255) / 256, 256, 0, stream>>>(esrc, edst, a_s, a_d, cur, ssort,
                                                   (float4*)asort, E);
    k_aggr<<<n, 256, 0, stream>>>(xp_b, a_s, a_d, offs, ssort, asort, biasg, h1_b, n);
    // hm = h1 @ Wm + bm + x  -> fp32 + bf16
    k_gemm<HF, 1><<<mb * (FD / 64), 256, 0, stream>>>(h1_b, WmT, bm, x,
                                                      hm_b, hm_f, n, FD);
    // t = lrelu(hm @ W1 + b1) -> bf16
    k_gemm<FD, 2><<<mb * (FD / 64), 256, 0, stream>>>(hm_b, W1T, b1, nullptr,
                                                      t_b, nullptr, n, FD);
    // out = t @ W2 + b2 + hm
    k_gemm<FD, 3><<<mb * (FD / 64), 256, 0, stream>>>(t_b, W2T, b2, hm_f,
                                                      nullptr, out, n, FD);
}

// Round 3
// 451.698 us; speedup vs baseline: 1.7043x; 1.0960x over previous
//
#include <hip/hip_runtime.h>

#define FD 128
#define NH 4
#define HF 512

typedef __attribute__((ext_vector_type(8))) short short8;
typedef __attribute__((ext_vector_type(4))) float v4f;

__device__ __forceinline__ float lrelu(float x, float s) { return x > 0.f ? x : s * x; }

__device__ __forceinline__ unsigned short f2bf(float f) {
    unsigned int u = __float_as_uint(f);
    u += 0x7FFFu + ((u >> 16) & 1u);          // RNE
    return (unsigned short)(u >> 16);
}
__device__ __forceinline__ unsigned int pack2(float a, float b) {
    return (unsigned)f2bf(a) | ((unsigned)f2bf(b) << 16);
}

__device__ __forceinline__ void acc8_fma(const uint4& u, float w, float* acc) {
    acc[0] += __uint_as_float(u.x << 16) * w;
    acc[1] += __uint_as_float(u.x & 0xffff0000u) * w;
    acc[2] += __uint_as_float(u.y << 16) * w;
    acc[3] += __uint_as_float(u.y & 0xffff0000u) * w;
    acc[4] += __uint_as_float(u.z << 16) * w;
    acc[5] += __uint_as_float(u.z & 0xffff0000u) * w;
    acc[6] += __uint_as_float(u.w << 16) * w;
    acc[7] += __uint_as_float(u.w & 0xffff0000u) * w;
}

// ---------------- fused prep: cast x->bf16, 4 weight transpose-casts, degree count
__global__ __launch_bounds__(256) void k_prep(const float* __restrict__ x,
                                              unsigned short* __restrict__ xb,
                                              const float* __restrict__ Wg, unsigned short* __restrict__ WgT,
                                              const float* __restrict__ Wm, unsigned short* __restrict__ WmT,
                                              const float* __restrict__ W1, unsigned short* __restrict__ W1T,
                                              const float* __restrict__ W2, unsigned short* __restrict__ W2T,
                                              const int* __restrict__ dst, int* __restrict__ cnt,
                                              int n, int E) {
    const int t = threadIdx.x;
    int b = blockIdx.x;
    const int nCast = (n * FD / 8 + 255) / 256;
    const int nT1 = (FD * HF / 4 + 255) / 256;
    const int nT3 = (FD * FD / 4 + 255) / 256;
    if (b < nCast) {
        int i = b * 256 + t;
        if (i < n * FD / 8) {
            const float4* x4 = reinterpret_cast<const float4*>(x);
            float4 v0 = x4[i * 2], v1 = x4[i * 2 + 1];
            uint4 o;
            o.x = pack2(v0.x, v0.y); o.y = pack2(v0.z, v0.w);
            o.z = pack2(v1.x, v1.y); o.w = pack2(v1.z, v1.w);
            reinterpret_cast<uint4*>(xb)[i] = o;
        }
        return;
    }
    b -= nCast;
    if (b < nT1) {   // WgT[512][128] <- Wg[128][512]
        int i4 = (b * 256 + t) * 4;
        if (i4 < FD * HF) {
            int nn = i4 >> 7, k = i4 & 127;
            uint2 o;
            o.x = pack2(Wg[(size_t)k * HF + nn], Wg[(size_t)(k + 1) * HF + nn]);
            o.y = pack2(Wg[(size_t)(k + 2) * HF + nn], Wg[(size_t)(k + 3) * HF + nn]);
            *reinterpret_cast<uint2*>(&WgT[i4]) = o;
        }
        return;
    }
    b -= nT1;
    if (b < nT1) {   // WmT[128][512] <- Wm[512][128]
        int i4 = (b * 256 + t) * 4;
        if (i4 < HF * FD) {
            int nn = i4 >> 9, k = i4 & 511;
            uint2 o;
            o.x = pack2(Wm[(size_t)k * FD + nn], Wm[(size_t)(k + 1) * FD + nn]);
            o.y = pack2(Wm[(size_t)(k + 2) * FD + nn], Wm[(size_t)(k + 3) * FD + nn]);
            *reinterpret_cast<uint2*>(&WmT[i4]) = o;
        }
        return;
    }
    b -= nT1;
    if (b < nT3) {   // W1T[128][128]
        int i4 = (b * 256 + t) * 4;
        if (i4 < FD * FD) {
            int nn = i4 >> 7, k = i4 & 127;
            uint2 o;
            o.x = pack2(W1[(size_t)k * FD + nn], W1[(size_t)(k + 1) * FD + nn]);
            o.y = pack2(W1[(size_t)(k + 2) * FD + nn], W1[(size_t)(k + 3) * FD + nn]);
            *reinterpret_cast<uint2*>(&W1T[i4]) = o;
        }
        return;
    }
    b -= nT3;
    if (b < nT3) {   // W2T[128][128]
        int i4 = (b * 256 + t) * 4;
        if (i4 < FD * FD) {
            int nn = i4 >> 7, k = i4 & 127;
            uint2 o;
            o.x = pack2(W2[(size_t)k * FD + nn], W2[(size_t)(k + 1) * FD + nn]);
            o.y = pack2(W2[(size_t)(k + 2) * FD + nn], W2[(size_t)(k + 3) * FD + nn]);
            *reinterpret_cast<uint2*>(&W2T[i4]) = o;
        }
        return;
    }
    b -= nT3;
    {
        int i = b * 256 + t;
        if (i < E) atomicAdd(&cnt[dst[i]], 1);
    }
}

// ---------------- generic MFMA GEMM: C[n x Ntot] = A[n x K](bf16) @ BT[Ntot x K](bf16)
// Block = 64 rows x (NT*16) cols.
// MODE 0: store bf16 + fused a_src/a_dst (requires NT=8 so block covers one head)
// MODE 1: +bias +resid(fp32) -> store fp32 AND bf16   (mha)
// MODE 2: lrelu(+bias,0.01) -> store bf16              (ffn1)
// MODE 3: +bias +resid -> store fp32                   (ffn2)
template <int K, int NT, int MODE>
__global__ __launch_bounds__(256) void k_gemm(const unsigned short* __restrict__ A,
                                              const unsigned short* __restrict__ BT,
                                              const float* __restrict__ bias,
                                              const float* __restrict__ resid,
                                              unsigned short* __restrict__ outb,
                                              float* __restrict__ outf,
                                              const float* __restrict__ att_s,
                                              const float* __restrict__ att_d,
                                              float* __restrict__ a_s,
                                              float* __restrict__ a_d,
                                              int n, int Ntot) {
    const int TB = NT * 16;
    const int nb = Ntot / TB;
    const int n0 = (blockIdx.x % nb) * TB;
    const int m0 = (blockIdx.x / nb) * 64;
    const int wv = threadIdx.x >> 6, l = threadIdx.x & 63;
    const int mw = m0 + wv * 16;
    const int rA = l & 15;
    const int kg = (l >> 4) * 8;
    const int amr = min(mw + rA, n - 1);

    v4f acc[NT];
#pragma unroll
    for (int t = 0; t < NT; ++t) acc[t] = (v4f){0.f, 0.f, 0.f, 0.f};

#pragma unroll 4
    for (int kk = 0; kk < K / 32; ++kk) {
        short8 a = *reinterpret_cast<const short8*>(&A[(size_t)amr * K + kk * 32 + kg]);
#pragma unroll
        for (int nt = 0; nt < NT; ++nt) {
            short8 b = *reinterpret_cast<const short8*>(
                &BT[(size_t)(n0 + nt * 16 + rA) * K + kk * 32 + kg]);
            acc[nt] = __builtin_amdgcn_mfma_f32_16x16x32_bf16(a, b, acc[nt], 0, 0, 0);
        }
    }

    if (MODE == 0) {
        const int head = n0 >> 7;
        float ps[4] = {0.f, 0.f, 0.f, 0.f}, pd[4] = {0.f, 0.f, 0.f, 0.f};
#pragma unroll
        for (int nt = 0; nt < NT; ++nt) {
            const int col = n0 + nt * 16 + rA;
            const float asv = att_s[(head << 7) + nt * 16 + rA];
            const float adv = att_d[(head << 7) + nt * 16 + rA];
#pragma unroll
            for (int i = 0; i < 4; ++i) {
                const int r = mw + (l >> 4) * 4 + i;
                float v = acc[nt][i];
                if (r < n) outb[(size_t)r * Ntot + col] = f2bf(v);
                ps[i] += v * asv;
                pd[i] += v * adv;
            }
        }
#pragma unroll
        for (int i = 0; i < 4; ++i) {
#pragma unroll
            for (int d = 1; d < 16; d <<= 1) {
                ps[i] += __shfl_xor(ps[i], d);
                pd[i] += __shfl_xor(pd[i], d);
            }
        }
        if (rA == 0) {
#pragma unroll
            for (int i = 0; i < 4; ++i) {
                const int r = mw + (l >> 4) * 4 + i;
                if (r < n) {
                    a_s[r * NH + head] = ps[i];
                    a_d[r * NH + head] = pd[i];
                }
            }
        }
    } else {
#pragma unroll
        for (int nt = 0; nt < NT; ++nt) {
            const int col = n0 + nt * 16 + rA;
#pragma unroll
            for (int i = 0; i < 4; ++i) {
                const int r = mw + (l >> 4) * 4 + i;
                if (r < n) {
                    float v = acc[nt][i];
                    if (MODE == 1) {
                        v += bias[col] + resid[(size_t)r * Ntot + col];
                        outf[(size_t)r * Ntot + col] = v;
                        outb[(size_t)r * Ntot + col] = f2bf(v);
                    } else if (MODE == 2) {
                        v = lrelu(v + bias[col], 0.01f);
                        outb[(size_t)r * Ntot + col] = f2bf(v);
                    } else {
                        v += bias[col] + resid[(size_t)r * Ntot + col];
                        outf[(size_t)r * Ntot + col] = v;
                    }
                }
            }
        }
    }
}

// ---------------- exclusive scan -> off[0..n], cur[i]=off[i]
__global__ __launch_bounds__(1024) void k_scan(const int* __restrict__ cnt,
                                               int* __restrict__ off,
                                               int* __restrict__ cur, int n) {
    __shared__ int stot[16];
    const int t = threadIdx.x;
    const int lane = t & 63, wid = t >> 6;
    if (t == 0) off[0] = 0;
    int carry = 0;
    for (int base = 0; base < n; base += 1024) {
        int idx = base + t;
        int v = (idx < n) ? cnt[idx] : 0;
        int incl = v;
#pragma unroll
        for (int d = 1; d < 64; d <<= 1) {
            int o = __shfl_up(incl, d);
            if (lane >= d) incl += o;
        }
        if (lane == 63) stot[wid] = incl;
        __syncthreads();
        int woff = 0, total = 0;
#pragma unroll
        for (int i = 0; i < 16; ++i) {
            int s = stot[i];
            if (i < wid) woff += s;
            total += s;
        }
        incl += woff;
        if (idx < n) { off[idx + 1] = carry + incl; cur[idx] = carry + incl - v; }
        carry += total;
        __syncthreads();
    }
}

// ---------------- scatter edges into CSR slots, with leaky(0.2) logits
__global__ __launch_bounds__(256) void k_scatter(const int* __restrict__ es,
                                                 const int* __restrict__ ed,
                                                 const float* __restrict__ a_s,
                                                 const float* __restrict__ a_d,
                                                 int* __restrict__ cur,
                                                 int* __restrict__ ssort,
                                                 float4* __restrict__ asort, int e) {
    int i = blockIdx.x * 256 + threadIdx.x;
    if (i >= e) return;
    int s = es[i], d = ed[i];
    const float4 as = *reinterpret_cast<const float4*>(&a_s[(size_t)s * NH]);
    const float4 ad = *reinterpret_cast<const float4*>(&a_d[(size_t)d * NH]);
    float4 al;
    al.x = lrelu(as.x + ad.x, 0.2f);
    al.y = lrelu(as.y + ad.y, 0.2f);
    al.z = lrelu(as.z + ad.z, 0.2f);
    al.w = lrelu(as.w + ad.w, 0.2f);
    int pos = atomicAdd(&cur[d], 1);
    ssort[pos] = s;
    asort[pos] = al;
}

// ---------------- per-node (one wave each) softmax + weighted aggregation -> h1 bf16
__global__ __launch_bounds__(256) void k_aggr(const unsigned short* __restrict__ xpb,
                                              const float* __restrict__ a_s,
                                              const float* __restrict__ a_d,
                                              const int* __restrict__ off,
                                              const int* __restrict__ ssort,
                                              const float* __restrict__ asort,
                                              const float* __restrict__ bias,
                                              unsigned short* __restrict__ h1b, int n) {
    const int w = threadIdx.x >> 6, l = threadIdx.x & 63;
    const int node = blockIdx.x * 4 + w;
    if (node >= n) return;
    const int h = l >> 4, e16 = l & 15;
    const int o0 = off[node], deg = off[node + 1] - o0;
    const float aS = lrelu(a_s[node * NH + h] + a_d[node * NH + h], 0.2f);

    // segment max (16 lanes of this head stride the edge list)
    float m = aS;
    for (int e = e16; e < deg; e += 16) m = fmaxf(m, asort[(size_t)(o0 + e) * 4 + h]);
#pragma unroll
    for (int d = 1; d < 16; d <<= 1) m = fmaxf(m, __shfl_xor(m, d));
    // denom
    float ss = (e16 == 0) ? __expf(aS - m) : 0.f;
    for (int e = e16; e < deg; e += 16) ss += __expf(asort[(size_t)(o0 + e) * 4 + h] - m);
#pragma unroll
    for (int d = 1; d < 16; d <<= 1) ss += __shfl_xor(ss, d);
    const float inv = 1.f / ss;

    // features: lane covers [8l, 8l+8) of the 512; its head == h
    const size_t fb = (size_t)l * 8;
    float acc[8];
    {
        const float wS = __expf(aS - m) * inv;
        uint4 u = *reinterpret_cast<const uint4*>(&xpb[(size_t)node * HF + fb]);
        acc[0] = __uint_as_float(u.x << 16) * wS;
        acc[1] = __uint_as_float(u.x & 0xffff0000u) * wS;
        acc[2] = __uint_as_float(u.y << 16) * wS;
        acc[3] = __uint_as_float(u.y & 0xffff0000u) * wS;
        acc[4] = __uint_as_float(u.z << 16) * wS;
        acc[5] = __uint_as_float(u.z & 0xffff0000u) * wS;
        acc[6] = __uint_as_float(u.w << 16) * wS;
        acc[7] = __uint_as_float(u.w & 0xffff0000u) * wS;
    }
    const int* sso = ssort + o0;
    const float* aso = asort + (size_t)o0 * 4 + h;
    int e = 0;
    for (; e + 4 <= deg; e += 4) {
        int s0 = sso[e], s1 = sso[e + 1], s2 = sso[e + 2], s3 = sso[e + 3];
        float w0 = __expf(aso[4 * e] - m) * inv;
        float w1 = __expf(aso[4 * e + 4] - m) * inv;
        float w2 = __expf(aso[4 * e + 8] - m) * inv;
        float w3 = __expf(aso[4 * e + 12] - m) * inv;
        uint4 u0 = *reinterpret_cast<const uint4*>(&xpb[(size_t)s0 * HF + fb]);
        uint4 u1 = *reinterpret_cast<const uint4*>(&xpb[(size_t)s1 * HF + fb]);
        uint4 u2 = *reinterpret_cast<const uint4*>(&xpb[(size_t)s2 * HF + fb]);
        uint4 u3 = *reinterpret_cast<const uint4*>(&xpb[(size_t)s3 * HF + fb]);
        acc8_fma(u0, w0, acc);
        acc8_fma(u1, w1, acc);
        acc8_fma(u2, w2, acc);
        acc8_fma(u3, w3, acc);
    }
    for (; e < deg; ++e) {
        int s0 = sso[e];
        float w0 = __expf(aso[4 * e] - m) * inv;
        uint4 u0 = *reinterpret_cast<const uint4*>(&xpb[(size_t)s0 * HF + fb]);
        acc8_fma(u0, w0, acc);
    }
    const float4 b0 = *reinterpret_cast<const float4*>(&bias[fb]);
    const float4 b1 = *reinterpret_cast<const float4*>(&bias[fb + 4]);
    acc[0] = lrelu(acc[0] + b0.x, 0.01f);
    acc[1] = lrelu(acc[1] + b0.y, 0.01f);
    acc[2] = lrelu(acc[2] + b0.z, 0.01f);
    acc[3] = lrelu(acc[3] + b0.w, 0.01f);
    acc[4] = lrelu(acc[4] + b1.x, 0.01f);
    acc[5] = lrelu(acc[5] + b1.y, 0.01f);
    acc[6] = lrelu(acc[6] + b1.z, 0.01f);
    acc[7] = lrelu(acc[7] + b1.w, 0.01f);
    uint4 o;
    o.x = pack2(acc[0], acc[1]); o.y = pack2(acc[2], acc[3]);
    o.z = pack2(acc[4], acc[5]); o.w = pack2(acc[6], acc[7]);
    *reinterpret_cast<uint4*>(&h1b[(size_t)node * HF + fb]) = o;
}

extern "C" void kernel_launch(void* const* d_in, const int* in_sizes, int n_in,
                              void* d_out, int out_size, void* d_ws, size_t ws_size,
                              hipStream_t stream) {
    const float* x     = (const float*)d_in[0];
    const int*   ei    = (const int*)d_in[1];
    const float* Wg    = (const float*)d_in[2];
    const float* att_s = (const float*)d_in[3];
    const float* att_d = (const float*)d_in[4];
    const float* biasg = (const float*)d_in[5];
    const float* Wm    = (const float*)d_in[6];
    const float* bm    = (const float*)d_in[7];
    const float* W1    = (const float*)d_in[8];
    const float* b1    = (const float*)d_in[9];
    const float* W2    = (const float*)d_in[10];
    const float* b2    = (const float*)d_in[11];
    float* out = (float*)d_out;

    const int n = in_sizes[0] / FD;
    const int E = in_sizes[1] / 2;
    const int* esrc = ei;
    const int* edst = ei + E;

    char* w = (char*)d_ws;
    size_t o = 0;
    auto alloc = [&](size_t b) { void* p = w + o; o = (o + b + 255) & ~(size_t)255; return p; };
    unsigned short* x_b  = (unsigned short*)alloc((size_t)n * FD * 2);
    unsigned short* WgT  = (unsigned short*)alloc((size_t)FD * HF * 2);
    unsigned short* WmT  = (unsigned short*)alloc((size_t)HF * FD * 2);
    unsigned short* W1T  = (unsigned short*)alloc((size_t)FD * FD * 2);
    unsigned short* W2T  = (unsigned short*)alloc((size_t)FD * FD * 2);
    unsigned short* xp_b = (unsigned short*)alloc((size_t)n * HF * 2);
    unsigned short* h1_b = (unsigned short*)alloc((size_t)n * HF * 2);
    float*          hm_f = (float*)alloc((size_t)n * FD * 4);
    unsigned short* hm_b = (unsigned short*)alloc((size_t)n * FD * 2);
    unsigned short* t_b  = (unsigned short*)alloc((size_t)n * FD * 2);
    float* a_s   = (float*)alloc((size_t)n * NH * 4);
    float* a_d   = (float*)alloc((size_t)n * NH * 4);
    int*   cnt   = (int*)alloc((size_t)n * 4);
    int*   offs  = (int*)alloc((size_t)(n + 1) * 4);
    int*   cur   = (int*)alloc((size_t)n * 4);
    int*   ssort = (int*)alloc((size_t)E * 4);
    float* asort = (float*)alloc((size_t)E * 16);

    hipMemsetAsync(cnt, 0, (size_t)n * 4, stream);

    const int nCast = (n * FD / 8 + 255) / 256;
    const int nT1 = (FD * HF / 4 + 255) / 256;
    const int nT3 = (FD * FD / 4 + 255) / 256;
    const int nCnt = (E + 255) / 256;
    const int gprep = nCast + 2 * nT1 + 2 * nT3 + nCnt;
    k_prep<<<gprep, 256, 0, stream>>>(x, x_b, Wg, WgT, Wm, WmT, W1, W1T, W2, W2T,
                                      edst, cnt, n, E);

    const int mb = (n + 63) / 64;
    // xp = x @ Wg -> bf16, with fused a_src/a_dst
    k_gemm<FD, 8, 0><<<mb * (HF / 128), 256, 0, stream>>>(
        x_b, WgT, nullptr, nullptr, xp_b, nullptr, att_s, att_d, a_s, a_d, n, HF);
    k_scan<<<1, 1024, 0, stream>>>(cnt, offs, cur, n);
    k_scatter<<<(E + 255) / 256, 256, 0, stream>>>(esrc, edst, a_s, a_d, cur, ssort,
                                                   (float4*)asort, E);
    k_aggr<<<(n + 3) / 4, 256, 0, stream>>>(xp_b, a_s, a_d, offs, ssort, asort, biasg,
                                            h1_b, n);
    // hm = h1 @ Wm + bm + x -> fp32 + bf16
    k_gemm<HF, 8, 1><<<mb, 256, 0, stream>>>(h1_b, WmT, bm, x, hm_b, hm_f,
                                             nullptr, nullptr, nullptr, nullptr, n, FD);
    // t = lrelu(hm @ W1 + b1) -> bf16
    k_gemm<FD, 8, 2><<<mb, 256, 0, stream>>>(hm_b, W1T, b1, nullptr, t_b, nullptr,
                                             nullptr, nullptr, nullptr, nullptr, n, FD);
    // out = t @ W2 + b2 + hm
    k_gemm<FD, 8, 3><<<mb, 256, 0, stream>>>(t_b, W2T, b2, hm_f, nullptr, out,
                                             nullptr, nullptr, nullptr, nullptr, n, FD);
}

// Round 4
// 395.720 us; speedup vs baseline: 1.9454x; 1.1415x over previous
//
#include <hip/hip_runtime.h>

#define FD 128
#define NH 4
#define HF 512

typedef __attribute__((ext_vector_type(8))) short short8;
typedef __attribute__((ext_vector_type(4))) float v4f;

__device__ __forceinline__ float lrelu(float x, float s) { return x > 0.f ? x : s * x; }

__device__ __forceinline__ unsigned short f2bf(float f) {
    unsigned int u = __float_as_uint(f);
    u += 0x7FFFu + ((u >> 16) & 1u);          // RNE
    return (unsigned short)(u >> 16);
}
__device__ __forceinline__ unsigned int pack2(float a, float b) {
    return (unsigned)f2bf(a) | ((unsigned)f2bf(b) << 16);
}
__device__ __forceinline__ float bf2f(unsigned short u) {
    return __uint_as_float((unsigned int)u << 16);
}

__device__ __forceinline__ void acc8_fma(const uint4& u, float w, float* acc) {
    acc[0] += __uint_as_float(u.x << 16) * w;
    acc[1] += __uint_as_float(u.x & 0xffff0000u) * w;
    acc[2] += __uint_as_float(u.y << 16) * w;
    acc[3] += __uint_as_float(u.y & 0xffff0000u) * w;
    acc[4] += __uint_as_float(u.z << 16) * w;
    acc[5] += __uint_as_float(u.z & 0xffff0000u) * w;
    acc[6] += __uint_as_float(u.w << 16) * w;
    acc[7] += __uint_as_float(u.w & 0xffff0000u) * w;
}

// ---------------- fused prep: cast x->bf16, 4 weight transpose-casts, degree count
__global__ __launch_bounds__(256) void k_prep(const float* __restrict__ x,
                                              unsigned short* __restrict__ xb,
                                              const float* __restrict__ Wg, unsigned short* __restrict__ WgT,
                                              const float* __restrict__ Wm, unsigned short* __restrict__ WmT,
                                              const float* __restrict__ W1, unsigned short* __restrict__ W1T,
                                              const float* __restrict__ W2, unsigned short* __restrict__ W2T,
                                              const int* __restrict__ dst, int* __restrict__ cnt,
                                              int n, int E) {
    const int t = threadIdx.x;
    int b = blockIdx.x;
    const int nCast = (n * FD / 8 + 255) / 256;
    const int nT1 = (FD * HF / 4 + 255) / 256;
    const int nT3 = (FD * FD / 4 + 255) / 256;
    if (b < nCast) {
        int i = b * 256 + t;
        if (i < n * FD / 8) {
            const float4* x4 = reinterpret_cast<const float4*>(x);
            float4 v0 = x4[i * 2], v1 = x4[i * 2 + 1];
            uint4 o;
            o.x = pack2(v0.x, v0.y); o.y = pack2(v0.z, v0.w);
            o.z = pack2(v1.x, v1.y); o.w = pack2(v1.z, v1.w);
            reinterpret_cast<uint4*>(xb)[i] = o;
        }
        return;
    }
    b -= nCast;
    if (b < nT1) {   // WgT[512][128] <- Wg[128][512]
        int i4 = (b * 256 + t) * 4;
        if (i4 < FD * HF) {
            int nn = i4 >> 7, k = i4 & 127;
            uint2 o;
            o.x = pack2(Wg[(size_t)k * HF + nn], Wg[(size_t)(k + 1) * HF + nn]);
            o.y = pack2(Wg[(size_t)(k + 2) * HF + nn], Wg[(size_t)(k + 3) * HF + nn]);
            *reinterpret_cast<uint2*>(&WgT[i4]) = o;
        }
        return;
    }
    b -= nT1;
    if (b < nT1) {   // WmT[128][512] <- Wm[512][128]
        int i4 = (b * 256 + t) * 4;
        if (i4 < HF * FD) {
            int nn = i4 >> 9, k = i4 & 511;
            uint2 o;
            o.x = pack2(Wm[(size_t)k * FD + nn], Wm[(size_t)(k + 1) * FD + nn]);
            o.y = pack2(Wm[(size_t)(k + 2) * FD + nn], Wm[(size_t)(k + 3) * FD + nn]);
            *reinterpret_cast<uint2*>(&WmT[i4]) = o;
        }
        return;
    }
    b -= nT1;
    if (b < nT3) {   // W1T[128][128]
        int i4 = (b * 256 + t) * 4;
        if (i4 < FD * FD) {
            int nn = i4 >> 7, k = i4 & 127;
            uint2 o;
            o.x = pack2(W1[(size_t)k * FD + nn], W1[(size_t)(k + 1) * FD + nn]);
            o.y = pack2(W1[(size_t)(k + 2) * FD + nn], W1[(size_t)(k + 3) * FD + nn]);
            *reinterpret_cast<uint2*>(&W1T[i4]) = o;
        }
        return;
    }
    b -= nT3;
    if (b < nT3) {   // W2T[128][128]
        int i4 = (b * 256 + t) * 4;
        if (i4 < FD * FD) {
            int nn = i4 >> 7, k = i4 & 127;
            uint2 o;
            o.x = pack2(W2[(size_t)k * FD + nn], W2[(size_t)(k + 1) * FD + nn]);
            o.y = pack2(W2[(size_t)(k + 2) * FD + nn], W2[(size_t)(k + 3) * FD + nn]);
            *reinterpret_cast<uint2*>(&W2T[i4]) = o;
        }
        return;
    }
    b -= nT3;
    {
        int i = b * 256 + t;
        if (i < E) atomicAdd(&cnt[dst[i]], 1);
    }
}

// ---------------- xp GEMM: xp[n x 512] = x_b @ WgT^T, fused a_src/a_dst epilogue.
// Block = 64 rows x 128 cols (one head).
__global__ __launch_bounds__(256) void k_xpgemm(const unsigned short* __restrict__ A,
                                                const unsigned short* __restrict__ BT,
                                                unsigned short* __restrict__ outb,
                                                const float* __restrict__ att_s,
                                                const float* __restrict__ att_d,
                                                float* __restrict__ a_s,
                                                float* __restrict__ a_d, int n) {
    const int nb = HF / 128;
    const int n0 = (blockIdx.x % nb) * 128;
    const int m0 = (blockIdx.x / nb) * 64;
    const int wv = threadIdx.x >> 6, l = threadIdx.x & 63;
    const int mw = m0 + wv * 16;
    const int rA = l & 15;
    const int kg = (l >> 4) * 8;
    const int amr = min(mw + rA, n - 1);

    v4f acc[8];
#pragma unroll
    for (int t = 0; t < 8; ++t) acc[t] = (v4f){0.f, 0.f, 0.f, 0.f};

#pragma unroll
    for (int kk = 0; kk < FD / 32; ++kk) {
        short8 a = *reinterpret_cast<const short8*>(&A[(size_t)amr * FD + kk * 32 + kg]);
#pragma unroll
        for (int nt = 0; nt < 8; ++nt) {
            short8 b = *reinterpret_cast<const short8*>(
                &BT[(size_t)(n0 + nt * 16 + rA) * FD + kk * 32 + kg]);
            acc[nt] = __builtin_amdgcn_mfma_f32_16x16x32_bf16(a, b, acc[nt], 0, 0, 0);
        }
    }

    const int head = n0 >> 7;
    float ps[4] = {0.f, 0.f, 0.f, 0.f}, pd[4] = {0.f, 0.f, 0.f, 0.f};
#pragma unroll
    for (int nt = 0; nt < 8; ++nt) {
        const int col = n0 + nt * 16 + rA;
        const float asv = att_s[(head << 7) + nt * 16 + rA];
        const float adv = att_d[(head << 7) + nt * 16 + rA];
#pragma unroll
        for (int i = 0; i < 4; ++i) {
            const int r = mw + (l >> 4) * 4 + i;
            float v = acc[nt][i];
            if (r < n) outb[(size_t)r * HF + col] = f2bf(v);
            ps[i] += v * asv;
            pd[i] += v * adv;
        }
    }
#pragma unroll
    for (int i = 0; i < 4; ++i) {
#pragma unroll
        for (int d = 1; d < 16; d <<= 1) {
            ps[i] += __shfl_xor(ps[i], d);
            pd[i] += __shfl_xor(pd[i], d);
        }
    }
    if (rA == 0) {
#pragma unroll
        for (int i = 0; i < 4; ++i) {
            const int r = mw + (l >> 4) * 4 + i;
            if (r < n) {
                a_s[r * NH + head] = ps[i];
                a_d[r * NH + head] = pd[i];
            }
        }
    }
}

// ---------------- multi-block exclusive scan (3 phases)
__global__ __launch_bounds__(1024) void k_scanA(const int* __restrict__ cnt,
                                                int* __restrict__ bsum, int n) {
    __shared__ int wtot[16];
    const int b = blockIdx.x, t = threadIdx.x;
    const int lane = t & 63, wid = t >> 6;
    const int idx = b * 4096 + t * 4;
    int s = 0;
    if (idx + 3 < n) {
        int4 v = *reinterpret_cast<const int4*>(&cnt[idx]);
        s = v.x + v.y + v.z + v.w;
    } else {
        for (int j = 0; j < 4; ++j) if (idx + j < n) s += cnt[idx + j];
    }
#pragma unroll
    for (int d = 1; d < 64; d <<= 1) s += __shfl_xor(s, d);
    if (lane == 0) wtot[wid] = s;
    __syncthreads();
    if (t == 0) {
        int tot = 0;
#pragma unroll
        for (int i = 0; i < 16; ++i) tot += wtot[i];
        bsum[b] = tot;
    }
}

__global__ void k_scanB(const int* __restrict__ bsum, int* __restrict__ bpre, int nb) {
    const int l = threadIdx.x;
    int v = (l < nb) ? bsum[l] : 0;
    int incl = v;
#pragma unroll
    for (int d = 1; d < 64; d <<= 1) {
        int o = __shfl_up(incl, d);
        if (l >= d) incl += o;
    }
    if (l < nb) bpre[l] = incl - v;
}

__global__ __launch_bounds__(1024) void k_scanC(const int* __restrict__ cnt,
                                                const int* __restrict__ bpre,
                                                int* __restrict__ off,
                                                int* __restrict__ cur, int n) {
    __shared__ int wtot[16];
    const int b = blockIdx.x, t = threadIdx.x;
    const int lane = t & 63, wid = t >> 6;
    const int idx = b * 4096 + t * 4;
    int4 v = make_int4(0, 0, 0, 0);
    if (idx + 3 < n) v = *reinterpret_cast<const int4*>(&cnt[idx]);
    else {
        if (idx < n) v.x = cnt[idx];
        if (idx + 1 < n) v.y = cnt[idx + 1];
        if (idx + 2 < n) v.z = cnt[idx + 2];
        if (idx + 3 < n) v.w = cnt[idx + 3];
    }
    const int p1 = v.x, p2 = p1 + v.y, p3 = p2 + v.z, ts = p3 + v.w;
    int incl = ts;
#pragma unroll
    for (int d = 1; d < 64; d <<= 1) {
        int o = __shfl_up(incl, d);
        if (lane >= d) incl += o;
    }
    if (lane == 63) wtot[wid] = incl;
    __syncthreads();
    int wbase = 0;
#pragma unroll
    for (int i = 0; i < 16; ++i) if (i < wid) wbase += wtot[i];
    const int base = bpre[b] + wbase + (incl - ts);
    if (idx < n)     { cur[idx] = base;          off[idx + 1] = base + p1; }
    if (idx + 1 < n) { cur[idx + 1] = base + p1; off[idx + 2] = base + p2; }
    if (idx + 2 < n) { cur[idx + 2] = base + p2; off[idx + 3] = base + p3; }
    if (idx + 3 < n) { cur[idx + 3] = base + p3; off[idx + 4] = base + ts; }
    if (b == 0 && t == 0) off[0] = 0;
}

// ---------------- scatter edges into CSR slots, with leaky(0.2) logits
__global__ __launch_bounds__(256) void k_scatter(const int* __restrict__ es,
                                                 const int* __restrict__ ed,
                                                 const float* __restrict__ a_s,
                                                 const float* __restrict__ a_d,
                                                 int* __restrict__ cur,
                                                 int* __restrict__ ssort,
                                                 float4* __restrict__ asort, int e) {
    int i = blockIdx.x * 256 + threadIdx.x;
    if (i >= e) return;
    int s = es[i], d = ed[i];
    const float4 as = *reinterpret_cast<const float4*>(&a_s[(size_t)s * NH]);
    const float4 ad = *reinterpret_cast<const float4*>(&a_d[(size_t)d * NH]);
    float4 al;
    al.x = lrelu(as.x + ad.x, 0.2f);
    al.y = lrelu(as.y + ad.y, 0.2f);
    al.z = lrelu(as.z + ad.z, 0.2f);
    al.w = lrelu(as.w + ad.w, 0.2f);
    int pos = atomicAdd(&cur[d], 1);
    ssort[pos] = s;
    asort[pos] = al;
}

// ---------------- per-node (one wave) online softmax-aggregation -> h1 bf16
// No max subtraction (logits ~N(0,1.4): exp is fp32-safe; identical math).
// 16-edge batches: coalesced index+logit loads, shfl-distributed, 16 gathers in flight.
__global__ __launch_bounds__(256) void k_aggr(const unsigned short* __restrict__ xpb,
                                              const float* __restrict__ a_s,
                                              const float* __restrict__ a_d,
                                              const int* __restrict__ off,
                                              const int* __restrict__ ssort,
                                              const float* __restrict__ asort,
                                              const float* __restrict__ bias,
                                              unsigned short* __restrict__ h1b, int n) {
    const int w = threadIdx.x >> 6, l = threadIdx.x & 63;
    const int node = blockIdx.x * 4 + w;
    if (node >= n) return;
    const int h = l >> 4, e16 = l & 15;
    const int o0 = off[node], deg = off[node + 1] - o0;
    const int grp = l & 48;                 // head group base lane
    const float aS = lrelu(a_s[node * NH + h] + a_d[node * NH + h], 0.2f);
    const float wS = __expf(aS);

    const size_t fb = (size_t)l * 8;
    float acc[8];
    float ss = wS;
    {
        uint4 u = *reinterpret_cast<const uint4*>(&xpb[(size_t)node * HF + fb]);
        acc[0] = __uint_as_float(u.x << 16) * wS;
        acc[1] = __uint_as_float(u.x & 0xffff0000u) * wS;
        acc[2] = __uint_as_float(u.y << 16) * wS;
        acc[3] = __uint_as_float(u.y & 0xffff0000u) * wS;
        acc[4] = __uint_as_float(u.z << 16) * wS;
        acc[5] = __uint_as_float(u.z & 0xffff0000u) * wS;
        acc[6] = __uint_as_float(u.w << 16) * wS;
        acc[7] = __uint_as_float(u.w & 0xffff0000u) * wS;
    }
    const int* sso = ssort + o0;
    const float* aso = asort + (size_t)o0 * 4 + h;   // lane reads slot (base+e16), own head -> wave-coalesced 256B

    int base = 0;
    for (; base + 16 <= deg; base += 16) {
        int sidx = sso[base + e16];
        float wl = __expf(aso[4 * (base + e16)]);
#pragma unroll
        for (int e = 0; e < 16; ++e) {
            int s = __shfl(sidx, grp | e);
            float wgt = __shfl(wl, grp | e);
            uint4 u = *reinterpret_cast<const uint4*>(&xpb[(size_t)s * HF + fb]);
            ss += wgt;
            acc8_fma(u, wgt, acc);
        }
    }
    const int rem = deg - base;
    if (rem > 0) {
        int sidx = 0;
        float wl = 0.f;
        if (e16 < rem) {
            sidx = sso[base + e16];
            wl = __expf(aso[4 * (base + e16)]);
        }
        for (int e = 0; e < rem; ++e) {
            int s = __shfl(sidx, grp | e);
            float wgt = __shfl(wl, grp | e);
            uint4 u = *reinterpret_cast<const uint4*>(&xpb[(size_t)s * HF + fb]);
            ss += wgt;
            acc8_fma(u, wgt, acc);
        }
    }
    const float inv = 1.f / ss;
    const float4 b0 = *reinterpret_cast<const float4*>(&bias[fb]);
    const float4 b1 = *reinterpret_cast<const float4*>(&bias[fb + 4]);
    acc[0] = lrelu(acc[0] * inv + b0.x, 0.01f);
    acc[1] = lrelu(acc[1] * inv + b0.y, 0.01f);
    acc[2] = lrelu(acc[2] * inv + b0.z, 0.01f);
    acc[3] = lrelu(acc[3] * inv + b0.w, 0.01f);
    acc[4] = lrelu(acc[4] * inv + b1.x, 0.01f);
    acc[5] = lrelu(acc[5] * inv + b1.y, 0.01f);
    acc[6] = lrelu(acc[6] * inv + b1.z, 0.01f);
    acc[7] = lrelu(acc[7] * inv + b1.w, 0.01f);
    uint4 o;
    o.x = pack2(acc[0], acc[1]); o.y = pack2(acc[2], acc[3]);
    o.z = pack2(acc[4], acc[5]); o.w = pack2(acc[6], acc[7]);
    *reinterpret_cast<uint4*>(&h1b[(size_t)node * HF + fb]) = o;
}

// ---------------- fused mha + ffn:
// hm = h1@Wm + bm + x (regs fp32 + LDS bf16); t = lrelu(hm@W1+b1) (LDS bf16);
// out = t@W2 + b2 + hm(regs). Block = 64 rows x full 128 cols.
__global__ __launch_bounds__(256) void k_mha_ffn(const unsigned short* __restrict__ h1b,
                                                 const unsigned short* __restrict__ WmT,
                                                 const float* __restrict__ bm,
                                                 const float* __restrict__ x,
                                                 const unsigned short* __restrict__ W1T,
                                                 const float* __restrict__ b1,
                                                 const unsigned short* __restrict__ W2T,
                                                 const float* __restrict__ b2,
                                                 float* __restrict__ out, int n) {
    __shared__ unsigned short hmS[64][136];  // 272B row stride: 16B-aligned, ~2-way banks
    __shared__ unsigned short tS[64][136];
    const int m0 = blockIdx.x * 64;
    const int wv = threadIdx.x >> 6, l = threadIdx.x & 63;
    const int rA = l & 15;
    const int kg = (l >> 4) * 8;
    const int mw = m0 + wv * 16;
    const int amr = min(mw + rA, n - 1);
    const int lr0 = wv * 16 + (l >> 4) * 4;     // local row base for C-layout writes

    v4f acc[8];
    float hmr[8][4];                             // fp32 hm kept for exact residual

    // ---- stage 0: hm = h1 @ Wm + bm + x   (K=512)
#pragma unroll
    for (int t = 0; t < 8; ++t) acc[t] = (v4f){0.f, 0.f, 0.f, 0.f};
#pragma unroll 4
    for (int kk = 0; kk < HF / 32; ++kk) {
        short8 a = *reinterpret_cast<const short8*>(&h1b[(size_t)amr * HF + kk * 32 + kg]);
#pragma unroll
        for (int nt = 0; nt < 8; ++nt) {
            short8 b = *reinterpret_cast<const short8*>(
                &WmT[(size_t)(nt * 16 + rA) * HF + kk * 32 + kg]);
            acc[nt] = __builtin_amdgcn_mfma_f32_16x16x32_bf16(a, b, acc[nt], 0, 0, 0);
        }
    }
#pragma unroll
    for (int nt = 0; nt < 8; ++nt) {
        const int col = nt * 16 + rA;
        const float bv = bm[col];
#pragma unroll
        for (int i = 0; i < 4; ++i) {
            const int r = min(mw + (l >> 4) * 4 + i, n - 1);
            float v = acc[nt][i] + bv + x[(size_t)r * FD + col];
            hmr[nt][i] = v;
            hmS[lr0 + i][col] = f2bf(v);
        }
    }
    __syncthreads();

    // ---- stage 1: t = lrelu(hm @ W1 + b1)   (K=128, A from LDS)
#pragma unroll
    for (int t = 0; t < 8; ++t) acc[t] = (v4f){0.f, 0.f, 0.f, 0.f};
#pragma unroll
    for (int kk = 0; kk < FD / 32; ++kk) {
        short8 a = *reinterpret_cast<const short8*>(&hmS[wv * 16 + rA][kk * 32 + kg]);
#pragma unroll
        for (int nt = 0; nt < 8; ++nt) {
            short8 b = *reinterpret_cast<const short8*>(
                &W1T[(size_t)(nt * 16 + rA) * FD + kk * 32 + kg]);
            acc[nt] = __builtin_amdgcn_mfma_f32_16x16x32_bf16(a, b, acc[nt], 0, 0, 0);
        }
    }
#pragma unroll
    for (int nt = 0; nt < 8; ++nt) {
        const int col = nt * 16 + rA;
        const float bv = b1[col];
#pragma unroll
        for (int i = 0; i < 4; ++i)
            tS[lr0 + i][col] = f2bf(lrelu(acc[nt][i] + bv, 0.01f));
    }
    __syncthreads();

    // ---- stage 2: out = t @ W2 + b2 + hm   (K=128, A from LDS)
#pragma unroll
    for (int t = 0; t < 8; ++t) acc[t] = (v4f){0.f, 0.f, 0.f, 0.f};
#pragma unroll
    for (int kk = 0; kk < FD / 32; ++kk) {
        short8 a = *reinterpret_cast<const short8*>(&tS[wv * 16 + rA][kk * 32 + kg]);
#pragma unroll
        for (int nt = 0; nt < 8; ++nt) {
            short8 b = *reinterpret_cast<const short8*>(
                &W2T[(size_t)(nt * 16 + rA) * FD + kk * 32 + kg]);
            acc[nt] = __builtin_amdgcn_mfma_f32_16x16x32_bf16(a, b, acc[nt], 0, 0, 0);
        }
    }
#pragma unroll
    for (int nt = 0; nt < 8; ++nt) {
        const int col = nt * 16 + rA;
        const float bv = b2[col];
#pragma unroll
        for (int i = 0; i < 4; ++i) {
            const int r = mw + (l >> 4) * 4 + i;
            if (r < n)
                out[(size_t)r * FD + col] = acc[nt][i] + bv + hmr[nt][i];
        }
    }
}

extern "C" void kernel_launch(void* const* d_in, const int* in_sizes, int n_in,
                              void* d_out, int out_size, void* d_ws, size_t ws_size,
                              hipStream_t stream) {
    const float* x     = (const float*)d_in[0];
    const int*   ei    = (const int*)d_in[1];
    const float* Wg    = (const float*)d_in[2];
    const float* att_s = (const float*)d_in[3];
    const float* att_d = (const float*)d_in[4];
    const float* biasg = (const float*)d_in[5];
    const float* Wm    = (const float*)d_in[6];
    const float* bm    = (const float*)d_in[7];
    const float* W1    = (const float*)d_in[8];
    const float* b1    = (const float*)d_in[9];
    const float* W2    = (const float*)d_in[10];
    const float* b2    = (const float*)d_in[11];
    float* out = (float*)d_out;

    const int n = in_sizes[0] / FD;
    const int E = in_sizes[1] / 2;
    const int* esrc = ei;
    const int* edst = ei + E;

    char* w = (char*)d_ws;
    size_t o = 0;
    auto alloc = [&](size_t b) { void* p = w + o; o = (o + b + 255) & ~(size_t)255; return p; };
    unsigned short* x_b  = (unsigned short*)alloc((size_t)n * FD * 2);
    unsigned short* WgT  = (unsigned short*)alloc((size_t)FD * HF * 2);
    unsigned short* WmT  = (unsigned short*)alloc((size_t)HF * FD * 2);
    unsigned short* W1T  = (unsigned short*)alloc((size_t)FD * FD * 2);
    unsigned short* W2T  = (unsigned short*)alloc((size_t)FD * FD * 2);
    unsigned short* xp_b = (unsigned short*)alloc((size_t)n * HF * 2);
    unsigned short* h1_b = (unsigned short*)alloc((size_t)n * HF * 2);
    float* a_s   = (float*)alloc((size_t)n * NH * 4);
    float* a_d   = (float*)alloc((size_t)n * NH * 4);
    int*   cnt   = (int*)alloc((size_t)n * 4);
    int*   offs  = (int*)alloc((size_t)(n + 1) * 4);
    int*   cur   = (int*)alloc((size_t)n * 4);
    int*   ssort = (int*)alloc((size_t)E * 4);
    float* asort = (float*)alloc((size_t)E * 16);
    int*   bsum  = (int*)alloc(256 * 4);
    int*   bpre  = (int*)alloc(256 * 4);

    hipMemsetAsync(cnt, 0, (size_t)n * 4, stream);

    const int nCast = (n * FD / 8 + 255) / 256;
    const int nT1 = (FD * HF / 4 + 255) / 256;
    const int nT3 = (FD * FD / 4 + 255) / 256;
    const int nCnt = (E + 255) / 256;
    k_prep<<<nCast + 2 * nT1 + 2 * nT3 + nCnt, 256, 0, stream>>>(
        x, x_b, Wg, WgT, Wm, WmT, W1, W1T, W2, W2T, edst, cnt, n, E);

    const int mb = (n + 63) / 64;
    k_xpgemm<<<mb * (HF / 128), 256, 0, stream>>>(x_b, WgT, xp_b, att_s, att_d,
                                                  a_s, a_d, n);
    const int SB = (n + 4095) / 4096;
    k_scanA<<<SB, 1024, 0, stream>>>(cnt, bsum, n);
    k_scanB<<<1, 64, 0, stream>>>(bsum, bpre, SB);
    k_scanC<<<SB, 1024, 0, stream>>>(cnt, bpre, offs, cur, n);
    k_scatter<<<(E + 255) / 256, 256, 0, stream>>>(esrc, edst, a_s, a_d, cur, ssort,
                                                   (float4*)asort, E);
    k_aggr<<<(n + 3) / 4, 256, 0, stream>>>(xp_b, a_s, a_d, offs, ssort, asort, biasg,
                                            h1_b, n);
    k_mha_ffn<<<mb, 256, 0, stream>>>(h1_b, WmT, bm, x, W1T, b1, W2T, b2, out, n);
}

// Round 5
// 389.531 us; speedup vs baseline: 1.9764x; 1.0159x over previous
//
#include <hip/hip_runtime.h>

#define FD 128
#define NH 4
#define HF 512

typedef __attribute__((ext_vector_type(8))) short short8;
typedef __attribute__((ext_vector_type(4))) float v4f;

__device__ __forceinline__ float lrelu(float x, float s) { return x > 0.f ? x : s * x; }

__device__ __forceinline__ unsigned short f2bf(float f) {
    unsigned int u = __float_as_uint(f);
    u += 0x7FFFu + ((u >> 16) & 1u);          // RNE
    return (unsigned short)(u >> 16);
}
__device__ __forceinline__ unsigned int pack2(float a, float b) {
    return (unsigned)f2bf(a) | ((unsigned)f2bf(b) << 16);
}

// ---------------- fused prep: cast x->bf16, weight transpose-casts, u=Wg_h@att, degree count
__global__ __launch_bounds__(256) void k_prep(const float* __restrict__ x,
                                              unsigned short* __restrict__ xb,
                                              const float* __restrict__ Wg, unsigned short* __restrict__ WgT,
                                              const float* __restrict__ Wm, unsigned short* __restrict__ WmT,
                                              const float* __restrict__ W1, unsigned short* __restrict__ W1T,
                                              const float* __restrict__ W2, unsigned short* __restrict__ W2T,
                                              const float* __restrict__ att_s,
                                              const float* __restrict__ att_d,
                                              float* __restrict__ U,
                                              const int* __restrict__ dst, int* __restrict__ cnt,
                                              int n, int E) {
    const int t = threadIdx.x;
    int b = blockIdx.x;
    const int nCast = (n * FD / 8 + 255) / 256;
    const int nT1 = (FD * HF / 4 + 255) / 256;
    const int nT3 = (FD * FD / 4 + 255) / 256;
    const int nU = 4;
    if (b < nCast) {
        int i = b * 256 + t;
        if (i < n * FD / 8) {
            const float4* x4 = reinterpret_cast<const float4*>(x);
            float4 v0 = x4[i * 2], v1 = x4[i * 2 + 1];
            uint4 o;
            o.x = pack2(v0.x, v0.y); o.y = pack2(v0.z, v0.w);
            o.z = pack2(v1.x, v1.y); o.w = pack2(v1.z, v1.w);
            reinterpret_cast<uint4*>(xb)[i] = o;
        }
        return;
    }
    b -= nCast;
    if (b < nT1) {   // WgT[512][128] <- Wg[128][512]
        int i4 = (b * 256 + t) * 4;
        if (i4 < FD * HF) {
            int nn = i4 >> 7, k = i4 & 127;
            uint2 o;
            o.x = pack2(Wg[(size_t)k * HF + nn], Wg[(size_t)(k + 1) * HF + nn]);
            o.y = pack2(Wg[(size_t)(k + 2) * HF + nn], Wg[(size_t)(k + 3) * HF + nn]);
            *reinterpret_cast<uint2*>(&WgT[i4]) = o;
        }
        return;
    }
    b -= nT1;
    if (b < nT1) {   // WmT[128][512] <- Wm[512][128]
        int i4 = (b * 256 + t) * 4;
        if (i4 < HF * FD) {
            int nn = i4 >> 9, k = i4 & 511;
            uint2 o;
            o.x = pack2(Wm[(size_t)k * FD + nn], Wm[(size_t)(k + 1) * FD + nn]);
            o.y = pack2(Wm[(size_t)(k + 2) * FD + nn], Wm[(size_t)(k + 3) * FD + nn]);
            *reinterpret_cast<uint2*>(&WmT[i4]) = o;
        }
        return;
    }
    b -= nT1;
    if (b < nT3) {   // W1T[128][128]
        int i4 = (b * 256 + t) * 4;
        if (i4 < FD * FD) {
            int nn = i4 >> 7, k = i4 & 127;
            uint2 o;
            o.x = pack2(W1[(size_t)k * FD + nn], W1[(size_t)(k + 1) * FD + nn]);
            o.y = pack2(W1[(size_t)(k + 2) * FD + nn], W1[(size_t)(k + 3) * FD + nn]);
            *reinterpret_cast<uint2*>(&W1T[i4]) = o;
        }
        return;
    }
    b -= nT3;
    if (b < nT3) {   // W2T[128][128]
        int i4 = (b * 256 + t) * 4;
        if (i4 < FD * FD) {
            int nn = i4 >> 7, k = i4 & 127;
            uint2 o;
            o.x = pack2(W2[(size_t)k * FD + nn], W2[(size_t)(k + 1) * FD + nn]);
            o.y = pack2(W2[(size_t)(k + 2) * FD + nn], W2[(size_t)(k + 3) * FD + nn]);
            *reinterpret_cast<uint2*>(&W2T[i4]) = o;
        }
        return;
    }
    b -= nT3;
    if (b < nU) {    // U[0..511]=u_s[h][k], U[512..1023]=u_d[h][k]; u[h][k]=sum_j Wg[k][h*128+j]*att[h][j]
        int idx = b * 256 + t;
        int type = idx >> 9, h = (idx >> 7) & 3, k = idx & 127;
        const float* att = type ? att_d : att_s;
        const float* wrow = &Wg[(size_t)k * HF + h * FD];
        const float* arow = &att[h * FD];
        float s = 0.f;
#pragma unroll 4
        for (int j = 0; j < FD; ++j) s += wrow[j] * arow[j];
        U[idx] = s;
        return;
    }
    b -= nU;
    {
        int i = b * 256 + t;
        if (i < E) atomicAdd(&cnt[dst[i]], 1);
    }
}

// ---------------- a_s[n,h] = x[n]·u_s[h], a_d[n,h] = x[n]·u_d[h]   (fp32)
__global__ __launch_bounds__(256) void k_alog(const float* __restrict__ x,
                                              const float* __restrict__ U,
                                              float* __restrict__ a_s,
                                              float* __restrict__ a_d, int n) {
    int idx = blockIdx.x * 256 + threadIdx.x;
    int node = idx >> 2, h = idx & 3;
    if (node >= n) return;
    const float4* xr = reinterpret_cast<const float4*>(&x[(size_t)node * FD]);
    const float4* us = reinterpret_cast<const float4*>(&U[h * FD]);
    const float4* ud = reinterpret_cast<const float4*>(&U[512 + h * FD]);
    float ps = 0.f, pd = 0.f;
#pragma unroll 8
    for (int j = 0; j < 32; ++j) {
        float4 v = xr[j], a = us[j], bb = ud[j];
        ps += v.x * a.x + v.y * a.y + v.z * a.z + v.w * a.w;
        pd += v.x * bb.x + v.y * bb.y + v.z * bb.z + v.w * bb.w;
    }
    a_s[node * NH + h] = ps;
    a_d[node * NH + h] = pd;
}

// ---------------- multi-block exclusive scan (3 phases)
__global__ __launch_bounds__(1024) void k_scanA(const int* __restrict__ cnt,
                                                int* __restrict__ bsum, int n) {
    __shared__ int wtot[16];
    const int b = blockIdx.x, t = threadIdx.x;
    const int lane = t & 63, wid = t >> 6;
    const int idx = b * 4096 + t * 4;
    int s = 0;
    if (idx + 3 < n) {
        int4 v = *reinterpret_cast<const int4*>(&cnt[idx]);
        s = v.x + v.y + v.z + v.w;
    } else {
        for (int j = 0; j < 4; ++j) if (idx + j < n) s += cnt[idx + j];
    }
#pragma unroll
    for (int d = 1; d < 64; d <<= 1) s += __shfl_xor(s, d);
    if (lane == 0) wtot[wid] = s;
    __syncthreads();
    if (t == 0) {
        int tot = 0;
#pragma unroll
        for (int i = 0; i < 16; ++i) tot += wtot[i];
        bsum[b] = tot;
    }
}

__global__ void k_scanB(const int* __restrict__ bsum, int* __restrict__ bpre, int nb) {
    const int l = threadIdx.x;
    int v = (l < nb) ? bsum[l] : 0;
    int incl = v;
#pragma unroll
    for (int d = 1; d < 64; d <<= 1) {
        int o = __shfl_up(incl, d);
        if (l >= d) incl += o;
    }
    if (l < nb) bpre[l] = incl - v;
}

__global__ __launch_bounds__(1024) void k_scanC(const int* __restrict__ cnt,
                                                const int* __restrict__ bpre,
                                                int* __restrict__ off,
                                                int* __restrict__ cur, int n) {
    __shared__ int wtot[16];
    const int b = blockIdx.x, t = threadIdx.x;
    const int lane = t & 63, wid = t >> 6;
    const int idx = b * 4096 + t * 4;
    int4 v = make_int4(0, 0, 0, 0);
    if (idx + 3 < n) v = *reinterpret_cast<const int4*>(&cnt[idx]);
    else {
        if (idx < n) v.x = cnt[idx];
        if (idx + 1 < n) v.y = cnt[idx + 1];
        if (idx + 2 < n) v.z = cnt[idx + 2];
        if (idx + 3 < n) v.w = cnt[idx + 3];
    }
    const int p1 = v.x, p2 = p1 + v.y, p3 = p2 + v.z, ts = p3 + v.w;
    int incl = ts;
#pragma unroll
    for (int d = 1; d < 64; d <<= 1) {
        int o = __shfl_up(incl, d);
        if (lane >= d) incl += o;
    }
    if (lane == 63) wtot[wid] = incl;
    __syncthreads();
    int wbase = 0;
#pragma unroll
    for (int i = 0; i < 16; ++i) if (i < wid) wbase += wtot[i];
    const int base = bpre[b] + wbase + (incl - ts);
    if (idx < n)     { cur[idx] = base;          off[idx + 1] = base + p1; }
    if (idx + 1 < n) { cur[idx + 1] = base + p1; off[idx + 2] = base + p2; }
    if (idx + 2 < n) { cur[idx + 2] = base + p2; off[idx + 3] = base + p3; }
    if (idx + 3 < n) { cur[idx + 3] = base + p3; off[idx + 4] = base + ts; }
    if (b == 0 && t == 0) off[0] = 0;
}

// ---------------- scatter edges into CSR slots, with leaky(0.2) logits
__global__ __launch_bounds__(256) void k_scatter(const int* __restrict__ es,
                                                 const int* __restrict__ ed,
                                                 const float* __restrict__ a_s,
                                                 const float* __restrict__ a_d,
                                                 int* __restrict__ cur,
                                                 int* __restrict__ ssort,
                                                 float4* __restrict__ asort, int e) {
    int i = blockIdx.x * 256 + threadIdx.x;
    if (i >= e) return;
    int s = es[i], d = ed[i];
    const float4 as = *reinterpret_cast<const float4*>(&a_s[(size_t)s * NH]);
    const float4 ad = *reinterpret_cast<const float4*>(&a_d[(size_t)d * NH]);
    float4 al;
    al.x = lrelu(as.x + ad.x, 0.2f);
    al.y = lrelu(as.y + ad.y, 0.2f);
    al.z = lrelu(as.z + ad.z, 0.2f);
    al.w = lrelu(as.w + ad.w, 0.2f);
    int pos = atomicAdd(&cur[d], 1);
    ssort[pos] = s;
    asort[pos] = al;
}

// ---------------- per-node (one wave) aggregation in x-space -> agg bf16 [n][h*128+k]
// Lane l owns x-features {2l,2l+1}; accumulates them for all 4 heads (8 regs).
// 16-edge batches: coalesced index+logit loads, shfl-distributed weights,
// one dword gather per lane per edge (wave = 256 B coalesced row).
__global__ __launch_bounds__(256) void k_aggr2(const unsigned short* __restrict__ xb,
                                               const float* __restrict__ a_s,
                                               const float* __restrict__ a_d,
                                               const int* __restrict__ off,
                                               const int* __restrict__ ssort,
                                               const float* __restrict__ asort,
                                               unsigned short* __restrict__ agg, int n) {
    const int w = threadIdx.x >> 6, l = threadIdx.x & 63;
    const int node = blockIdx.x * 4 + w;
    if (node >= n) return;
    const int e16 = l & 15;
    const int o0 = off[node], deg = off[node + 1] - o0;

    float wS[4];
#pragma unroll
    for (int hh = 0; hh < 4; ++hh)
        wS[hh] = __expf(lrelu(a_s[node * NH + hh] + a_d[node * NH + hh], 0.2f));

    float acc[8];   // [h][2 feats]
    {
        unsigned int ux = *reinterpret_cast<const unsigned int*>(&xb[(size_t)node * FD + 2 * l]);
        float f0 = __uint_as_float(ux << 16);
        float f1 = __uint_as_float(ux & 0xffff0000u);
#pragma unroll
        for (int hh = 0; hh < 4; ++hh) { acc[hh * 2] = f0 * wS[hh]; acc[hh * 2 + 1] = f1 * wS[hh]; }
    }
    const int* sso = ssort + o0;
    const float* aso = asort + (size_t)o0 * 4 + (l >> 4);
    float sswl = 0.f;      // partial denom for head (l>>4) over this lane's slots

    int base = 0;
    int sidx = 0; float wl = 0.f;
    if (16 <= deg) { sidx = sso[e16]; wl = __expf(aso[4 * e16]); }
    while (base + 16 <= deg) {
        const int nb2 = base + 16;
        int sN = 0; float wN = 0.f;
        if (nb2 + 16 <= deg) { sN = sso[nb2 + e16]; wN = __expf(aso[4 * (nb2 + e16)]); }
        sswl += wl;
#pragma unroll
        for (int e = 0; e < 16; ++e) {
            int s = __shfl(sidx, e);
            float w0 = __shfl(wl, e);
            float w1 = __shfl(wl, 16 + e);
            float w2 = __shfl(wl, 32 + e);
            float w3 = __shfl(wl, 48 + e);
            unsigned int u = *reinterpret_cast<const unsigned int*>(&xb[(size_t)s * FD + 2 * l]);
            float f0 = __uint_as_float(u << 16);
            float f1 = __uint_as_float(u & 0xffff0000u);
            acc[0] += f0 * w0; acc[1] += f1 * w0;
            acc[2] += f0 * w1; acc[3] += f1 * w1;
            acc[4] += f0 * w2; acc[5] += f1 * w2;
            acc[6] += f0 * w3; acc[7] += f1 * w3;
        }
        sidx = sN; wl = wN; base = nb2;
    }
    const int rem = deg - base;
    if (rem > 0) {
        int s2 = 0; float w2l = 0.f;
        if (e16 < rem) { s2 = sso[base + e16]; w2l = __expf(aso[4 * (base + e16)]); }
        sswl += w2l;
        for (int e = 0; e < rem; ++e) {
            int s = __shfl(s2, e);
            float w0 = __shfl(w2l, e);
            float w1 = __shfl(w2l, 16 + e);
            float w2 = __shfl(w2l, 32 + e);
            float w3 = __shfl(w2l, 48 + e);
            unsigned int u = *reinterpret_cast<const unsigned int*>(&xb[(size_t)s * FD + 2 * l]);
            float f0 = __uint_as_float(u << 16);
            float f1 = __uint_as_float(u & 0xffff0000u);
            acc[0] += f0 * w0; acc[1] += f1 * w0;
            acc[2] += f0 * w1; acc[3] += f1 * w1;
            acc[4] += f0 * w2; acc[5] += f1 * w2;
            acc[6] += f0 * w3; acc[7] += f1 * w3;
        }
    }
    // reduce per-head denom: sum sswl within each 16-lane group, then read all 4 groups
#pragma unroll
    for (int d = 1; d < 16; d <<= 1) sswl += __shfl_xor(sswl, d);
    float inv[4];
#pragma unroll
    for (int hh = 0; hh < 4; ++hh) inv[hh] = 1.f / (__shfl(sswl, hh * 16) + wS[hh]);
    // store: for head h, dword at agg[node*512 + h*128 + 2l] -> 256B coalesced per h
#pragma unroll
    for (int hh = 0; hh < 4; ++hh) {
        unsigned int o = pack2(acc[hh * 2] * inv[hh], acc[hh * 2 + 1] * inv[hh]);
        *reinterpret_cast<unsigned int*>(&agg[(size_t)node * HF + hh * FD + 2 * l]) = o;
    }
}

// ---------------- h1[:, h*128+j] = lrelu(sum_k agg[:,h*128+k]*WgT[h*128+j][k] + biasg, 0.01)
__global__ __launch_bounds__(256) void k_h1(const unsigned short* __restrict__ agg,
                                            const unsigned short* __restrict__ WgT,
                                            const float* __restrict__ biasg,
                                            unsigned short* __restrict__ h1b, int n) {
    const int head = blockIdx.x & 3;
    const int m0 = (blockIdx.x >> 2) * 64;
    const int wv = threadIdx.x >> 6, l = threadIdx.x & 63;
    const int mw = m0 + wv * 16;
    const int rA = l & 15;
    const int kg = (l >> 4) * 8;
    const int amr = min(mw + rA, n - 1);

    v4f acc[8];
#pragma unroll
    for (int t = 0; t < 8; ++t) acc[t] = (v4f){0.f, 0.f, 0.f, 0.f};

#pragma unroll
    for (int kk = 0; kk < FD / 32; ++kk) {
        short8 a = *reinterpret_cast<const short8*>(
            &agg[(size_t)amr * HF + head * FD + kk * 32 + kg]);
#pragma unroll
        for (int nt = 0; nt < 8; ++nt) {
            short8 b = *reinterpret_cast<const short8*>(
                &WgT[(size_t)(head * FD + nt * 16 + rA) * FD + kk * 32 + kg]);
            acc[nt] = __builtin_amdgcn_mfma_f32_16x16x32_bf16(a, b, acc[nt], 0, 0, 0);
        }
    }
#pragma unroll
    for (int nt = 0; nt < 8; ++nt) {
        const int col = head * FD + nt * 16 + rA;
        const float bv = biasg[col];
#pragma unroll
        for (int i = 0; i < 4; ++i) {
            const int r = mw + (l >> 4) * 4 + i;
            if (r < n)
                h1b[(size_t)r * HF + col] = f2bf(lrelu(acc[nt][i] + bv, 0.01f));
        }
    }
}

// ---------------- fused mha + ffn (unchanged from round 4)
__global__ __launch_bounds__(256) void k_mha_ffn(const unsigned short* __restrict__ h1b,
                                                 const unsigned short* __restrict__ WmT,
                                                 const float* __restrict__ bm,
                                                 const float* __restrict__ x,
                                                 const unsigned short* __restrict__ W1T,
                                                 const float* __restrict__ b1,
                                                 const unsigned short* __restrict__ W2T,
                                                 const float* __restrict__ b2,
                                                 float* __restrict__ out, int n) {
    __shared__ unsigned short hmS[64][136];
    __shared__ unsigned short tS[64][136];
    const int m0 = blockIdx.x * 64;
    const int wv = threadIdx.x >> 6, l = threadIdx.x & 63;
    const int rA = l & 15;
    const int kg = (l >> 4) * 8;
    const int mw = m0 + wv * 16;
    const int amr = min(mw + rA, n - 1);
    const int lr0 = wv * 16 + (l >> 4) * 4;

    v4f acc[8];
    float hmr[8][4];

    // ---- stage 0: hm = h1 @ Wm + bm + x   (K=512)
#pragma unroll
    for (int t = 0; t < 8; ++t) acc[t] = (v4f){0.f, 0.f, 0.f, 0.f};
#pragma unroll 4
    for (int kk = 0; kk < HF / 32; ++kk) {
        short8 a = *reinterpret_cast<const short8*>(&h1b[(size_t)amr * HF + kk * 32 + kg]);
#pragma unroll
        for (int nt = 0; nt < 8; ++nt) {
            short8 b = *reinterpret_cast<const short8*>(
                &WmT[(size_t)(nt * 16 + rA) * HF + kk * 32 + kg]);
            acc[nt] = __builtin_amdgcn_mfma_f32_16x16x32_bf16(a, b, acc[nt], 0, 0, 0);
        }
    }
#pragma unroll
    for (int nt = 0; nt < 8; ++nt) {
        const int col = nt * 16 + rA;
        const float bv = bm[col];
#pragma unroll
        for (int i = 0; i < 4; ++i) {
            const int r = min(mw + (l >> 4) * 4 + i, n - 1);
            float v = acc[nt][i] + bv + x[(size_t)r * FD + col];
            hmr[nt][i] = v;
            hmS[lr0 + i][col] = f2bf(v);
        }
    }
    __syncthreads();

    // ---- stage 1: t = lrelu(hm @ W1 + b1)
#pragma unroll
    for (int t = 0; t < 8; ++t) acc[t] = (v4f){0.f, 0.f, 0.f, 0.f};
#pragma unroll
    for (int kk = 0; kk < FD / 32; ++kk) {
        short8 a = *reinterpret_cast<const short8*>(&hmS[wv * 16 + rA][kk * 32 + kg]);
#pragma unroll
        for (int nt = 0; nt < 8; ++nt) {
            short8 b = *reinterpret_cast<const short8*>(
                &W1T[(size_t)(nt * 16 + rA) * FD + kk * 32 + kg]);
            acc[nt] = __builtin_amdgcn_mfma_f32_16x16x32_bf16(a, b, acc[nt], 0, 0, 0);
        }
    }
#pragma unroll
    for (int nt = 0; nt < 8; ++nt) {
        const int col = nt * 16 + rA;
        const float bv = b1[col];
#pragma unroll
        for (int i = 0; i < 4; ++i)
            tS[lr0 + i][col] = f2bf(lrelu(acc[nt][i] + bv, 0.01f));
    }
    __syncthreads();

    // ---- stage 2: out = t @ W2 + b2 + hm
#pragma unroll
    for (int t = 0; t < 8; ++t) acc[t] = (v4f){0.f, 0.f, 0.f, 0.f};
#pragma unroll
    for (int kk = 0; kk < FD / 32; ++kk) {
        short8 a = *reinterpret_cast<const short8*>(&tS[wv * 16 + rA][kk * 32 + kg]);
#pragma unroll
        for (int nt = 0; nt < 8; ++nt) {
            short8 b = *reinterpret_cast<const short8*>(
                &W2T[(size_t)(nt * 16 + rA) * FD + kk * 32 + kg]);
            acc[nt] = __builtin_amdgcn_mfma_f32_16x16x32_bf16(a, b, acc[nt], 0, 0, 0);
        }
    }
#pragma unroll
    for (int nt = 0; nt < 8; ++nt) {
        const int col = nt * 16 + rA;
        const float bv = b2[col];
#pragma unroll
        for (int i = 0; i < 4; ++i) {
            const int r = mw + (l >> 4) * 4 + i;
            if (r < n)
                out[(size_t)r * FD + col] = acc[nt][i] + bv + hmr[nt][i];
        }
    }
}

extern "C" void kernel_launch(void* const* d_in, const int* in_sizes, int n_in,
                              void* d_out, int out_size, void* d_ws, size_t ws_size,
                              hipStream_t stream) {
    const float* x     = (const float*)d_in[0];
    const int*   ei    = (const int*)d_in[1];
    const float* Wg    = (const float*)d_in[2];
    const float* att_s = (const float*)d_in[3];
    const float* att_d = (const float*)d_in[4];
    const float* biasg = (const float*)d_in[5];
    const float* Wm    = (const float*)d_in[6];
    const float* bm    = (const float*)d_in[7];
    const float* W1    = (const float*)d_in[8];
    const float* b1    = (const float*)d_in[9];
    const float* W2    = (const float*)d_in[10];
    const float* b2    = (const float*)d_in[11];
    float* out = (float*)d_out;

    const int n = in_sizes[0] / FD;
    const int E = in_sizes[1] / 2;
    const int* esrc = ei;
    const int* edst = ei + E;

    char* w = (char*)d_ws;
    size_t o = 0;
    auto alloc = [&](size_t b) { void* p = w + o; o = (o + b + 255) & ~(size_t)255; return p; };
    unsigned short* x_b  = (unsigned short*)alloc((size_t)n * FD * 2);
    unsigned short* WgT  = (unsigned short*)alloc((size_t)FD * HF * 2);
    unsigned short* WmT  = (unsigned short*)alloc((size_t)HF * FD * 2);
    unsigned short* W1T  = (unsigned short*)alloc((size_t)FD * FD * 2);
    unsigned short* W2T  = (unsigned short*)alloc((size_t)FD * FD * 2);
    float*          U    = (float*)alloc(1024 * 4);
    unsigned short* aggb = (unsigned short*)alloc((size_t)n * HF * 2);
    unsigned short* h1_b = (unsigned short*)alloc((size_t)n * HF * 2);
    float* a_s   = (float*)alloc((size_t)n * NH * 4);
    float* a_d   = (float*)alloc((size_t)n * NH * 4);
    int*   cnt   = (int*)alloc((size_t)n * 4);
    int*   offs  = (int*)alloc((size_t)(n + 1) * 4);
    int*   cur   = (int*)alloc((size_t)n * 4);
    int*   ssort = (int*)alloc((size_t)E * 4);
    float* asort = (float*)alloc((size_t)E * 16);
    int*   bsum  = (int*)alloc(256 * 4);
    int*   bpre  = (int*)alloc(256 * 4);

    hipMemsetAsync(cnt, 0, (size_t)n * 4, stream);

    const int nCast = (n * FD / 8 + 255) / 256;
    const int nT1 = (FD * HF / 4 + 255) / 256;
    const int nT3 = (FD * FD / 4 + 255) / 256;
    const int nU = 4;
    const int nCnt = (E + 255) / 256;
    k_prep<<<nCast + 2 * nT1 + 2 * nT3 + nU + nCnt, 256, 0, stream>>>(
        x, x_b, Wg, WgT, Wm, WmT, W1, W1T, W2, W2T, att_s, att_d, U, edst, cnt, n, E);

    k_alog<<<(n * 4 + 255) / 256, 256, 0, stream>>>(x, U, a_s, a_d, n);

    const int SB = (n + 4095) / 4096;
    k_scanA<<<SB, 1024, 0, stream>>>(cnt, bsum, n);
    k_scanB<<<1, 64, 0, stream>>>(bsum, bpre, SB);
    k_scanC<<<SB, 1024, 0, stream>>>(cnt, bpre, offs, cur, n);
    k_scatter<<<(E + 255) / 256, 256, 0, stream>>>(esrc, edst, a_s, a_d, cur, ssort,
                                                   (float4*)asort, E);
    k_aggr2<<<(n + 3) / 4, 256, 0, stream>>>(x_b, a_s, a_d, offs, ssort, asort, aggb, n);

    const int mb = (n + 63) / 64;
    k_h1<<<mb * 4, 256, 0, stream>>>(aggb, WgT, biasg, h1_b, n);
    k_mha_ffn<<<mb, 256, 0, stream>>>(h1_b, WmT, bm, x, W1T, b1, W2T, b2, out, n);
}